// Round 1
// baseline (918.762 us; speedup 1.0000x reference)
//
#include <hip/hip_runtime.h>

// HeteroSAGE on MI355X.
// Pipeline:
//   0. memset cnt+cursor
//   1. prep: fold Wr/b pairs per dst type
//   2. count: per-relation in-degree (int atomics)
//   3. scan: exclusive prefix sum -> CSR rowptr (1 block per relation)
//   4. fill: CSR column (src) lists (int atomics on cursor)
//   5. agg:  per-dst mean of src features (wave/node, float2/lane) -> agg[r]
//   6. gemm0 x2: h = relu(agg_a@Wl_a.T + agg_b@Wl_b.T + x@(Wr_a+Wr_b).T + b)
//   7. l1_transform x2: z_r = h@Wl1_r.T (N x 2), self term -> out
//   8. l1_agg x2: out += mean_r(z) via CSR walk
// Workspace: ~216 MB.

#define DIN 128
#define DH  256

// ---------------- prep: fold self-weights & biases ----------------
__global__ __launch_bounds__(256) void prep_kernel(
    const float* __restrict__ Wr0_tt, const float* __restrict__ Wr0_aa,
    const float* __restrict__ Wr0_at, const float* __restrict__ Wr0_ta,
    const float* __restrict__ bl0_tt, const float* __restrict__ bl0_aa,
    const float* __restrict__ bl0_at, const float* __restrict__ bl0_ta,
    const float* __restrict__ Wr1_tt, const float* __restrict__ Wr1_aa,
    const float* __restrict__ Wr1_at, const float* __restrict__ Wr1_ta,
    const float* __restrict__ bl1_tt, const float* __restrict__ bl1_aa,
    const float* __restrict__ bl1_at, const float* __restrict__ bl1_ta,
    float* __restrict__ Wr0c, float* __restrict__ b0c,
    float* __restrict__ Wr1c, float* __restrict__ b1c)
{
    int i = blockIdx.x * blockDim.x + threadIdx.x;
    if (i < DH * DIN) {
        Wr0c[i]            = Wr0_tt[i] + Wr0_at[i];   // dst = tx
        Wr0c[DH * DIN + i] = Wr0_aa[i] + Wr0_ta[i];   // dst = addr
    }
    if (i < DH) {
        b0c[i]      = bl0_tt[i] + bl0_at[i];
        b0c[DH + i] = bl0_aa[i] + bl0_ta[i];
    }
    if (i < 2 * DH) {
        Wr1c[i]          = Wr1_tt[i] + Wr1_at[i];
        Wr1c[2 * DH + i] = Wr1_aa[i] + Wr1_ta[i];
    }
    if (i < 2) {
        b1c[i]     = bl1_tt[i] + bl1_at[i];
        b1c[2 + i] = bl1_aa[i] + bl1_ta[i];
    }
}

// ---------------- CSR build ----------------
__global__ __launch_bounds__(256) void count_kernel(
    const int* __restrict__ e0, const int* __restrict__ e1,
    const int* __restrict__ e2, const int* __restrict__ e3,
    int* __restrict__ cnt, int E, int N)
{
    int r = blockIdx.y;
    const int* e = (r == 0) ? e0 : (r == 1) ? e1 : (r == 2) ? e2 : e3;
    int i = blockIdx.x * blockDim.x + threadIdx.x;
    if (i < E) {
        int d = e[E + i];               // dst row of the (2,E) edge array
        atomicAdd(&cnt[r * N + d], 1);
    }
}

__global__ __launch_bounds__(1024) void scan_kernel(
    const int* __restrict__ cnt, int* __restrict__ rowptr, int n)
{
    // one block per relation: exclusive prefix-sum of cnt -> rowptr
    const int r = blockIdx.x;
    const int* c = cnt + (size_t)r * n;
    int* rp = rowptr + (size_t)r * n;
    __shared__ int sdata[1024];
    __shared__ int carry;
    if (threadIdx.x == 0) carry = 0;
    __syncthreads();
    for (int base = 0; base < n; base += 1024) {
        int i = base + threadIdx.x;
        int v = (i < n) ? c[i] : 0;
        sdata[threadIdx.x] = v;
        __syncthreads();
        for (int off = 1; off < 1024; off <<= 1) {
            int t = (threadIdx.x >= off) ? sdata[threadIdx.x - off] : 0;
            __syncthreads();
            sdata[threadIdx.x] += t;
            __syncthreads();
        }
        int incl = sdata[threadIdx.x];
        if (i < n) rp[i] = carry + (incl - v);
        __syncthreads();
        if (threadIdx.x == 1023) carry += sdata[1023];
        __syncthreads();
    }
}

__global__ __launch_bounds__(256) void fill_kernel(
    const int* __restrict__ e0, const int* __restrict__ e1,
    const int* __restrict__ e2, const int* __restrict__ e3,
    const int* __restrict__ rowptr, int* __restrict__ cursor,
    int* __restrict__ col, int E, int N)
{
    int r = blockIdx.y;
    const int* e = (r == 0) ? e0 : (r == 1) ? e1 : (r == 2) ? e2 : e3;
    int i = blockIdx.x * blockDim.x + threadIdx.x;
    if (i < E) {
        int s = e[i];
        int d = e[E + i];
        int pos = rowptr[r * N + d] + atomicAdd(&cursor[r * N + d], 1);
        col[(size_t)r * E + pos] = s;
    }
}

// ---------------- layer-0 mean aggregation (wave per dst node) ----------------
__global__ __launch_bounds__(256) void agg_kernel(
    const float* __restrict__ x_tx, const float* __restrict__ x_addr,
    const int* __restrict__ rowptr, const int* __restrict__ cnt,
    const int* __restrict__ col, float* __restrict__ agg, int N, int E)
{
    int r = blockIdx.y;                       // 0=tt 1=aa 2=at 3=ta
    const float* xs = (r == 0 || r == 3) ? x_tx : x_addr;  // src type
    int wave = threadIdx.x >> 6;
    int lane = threadIdx.x & 63;
    int node = blockIdx.x * 4 + wave;
    if (node >= N) return;
    int base = rowptr[r * N + node];
    int c    = cnt[r * N + node];
    const int* cl = col + (size_t)r * E + base;
    float ax = 0.f, ay = 0.f;
    for (int e = 0; e < c; ++e) {
        int s = cl[e];
        float2 v = *(const float2*)(xs + (size_t)s * DIN + lane * 2);
        ax += v.x; ay += v.y;
    }
    float sc = 1.0f / fmaxf((float)c, 1.0f);
    float2* orow = (float2*)(agg + ((size_t)r * N + node) * DIN);
    orow[lane] = make_float2(ax * sc, ay * sc);
}

// ---------------- layer-0 GEMM: out = relu(A0@W0.T + A1@W1.T + A2@W2.T + b) ----------------
// A_i: [M x 128] row-major.  W_i: [256 x 128] row-major.  out: [M x 256].
__global__ __launch_bounds__(256) void gemm0_kernel(
    const float* __restrict__ A0, const float* __restrict__ A1, const float* __restrict__ A2,
    const float* __restrict__ W0, const float* __restrict__ W1, const float* __restrict__ W2,
    const float* __restrict__ bias, float* __restrict__ outp, int M)
{
    __shared__ float Ast[16][68];   // A tile transposed [k][m], padded
    __shared__ float Bs[16][64];    // B tile [k][n] where B[k][n] = W[n][k]
    const int t  = threadIdx.x;
    const int tx = t & 15;          // n quad
    const int ty = t >> 4;          // m quad (0..15)
    const int lr = t >> 2;          // load row (0..63)
    const int lk = (t & 3) * 4;     // load k offset
    const int m0 = blockIdx.x * 64;
    const int n0 = blockIdx.y * 64;

    float acc[4][4] = {};
    const float* As_[3] = {A0, A1, A2};
    const float* Ws_[3] = {W0, W1, W2};

    for (int seg = 0; seg < 3; ++seg) {
        const float* A = As_[seg];
        const float* W = Ws_[seg];
        for (int ks = 0; ks < DIN; ks += 16) {
            __syncthreads();
            {
                int row = m0 + lr;
                float4 v = make_float4(0.f, 0.f, 0.f, 0.f);
                if (row < M) v = *(const float4*)(A + (size_t)row * DIN + ks + lk);
                Ast[lk + 0][lr] = v.x; Ast[lk + 1][lr] = v.y;
                Ast[lk + 2][lr] = v.z; Ast[lk + 3][lr] = v.w;
            }
            {
                float4 v = *(const float4*)(W + (size_t)(n0 + lr) * DIN + ks + lk);
                Bs[lk + 0][lr] = v.x; Bs[lk + 1][lr] = v.y;
                Bs[lk + 2][lr] = v.z; Bs[lk + 3][lr] = v.w;
            }
            __syncthreads();
#pragma unroll
            for (int k = 0; k < 16; ++k) {
                float4 a = *(const float4*)&Ast[k][ty * 4];
                float4 b = *(const float4*)&Bs[k][tx * 4];
                acc[0][0] += a.x * b.x; acc[0][1] += a.x * b.y; acc[0][2] += a.x * b.z; acc[0][3] += a.x * b.w;
                acc[1][0] += a.y * b.x; acc[1][1] += a.y * b.y; acc[1][2] += a.y * b.z; acc[1][3] += a.y * b.w;
                acc[2][0] += a.z * b.x; acc[2][1] += a.z * b.y; acc[2][2] += a.z * b.z; acc[2][3] += a.z * b.w;
                acc[3][0] += a.w * b.x; acc[3][1] += a.w * b.y; acc[3][2] += a.w * b.z; acc[3][3] += a.w * b.w;
            }
        }
    }

    float b0 = bias[n0 + tx * 4 + 0];
    float b1 = bias[n0 + tx * 4 + 1];
    float b2 = bias[n0 + tx * 4 + 2];
    float b3 = bias[n0 + tx * 4 + 3];
#pragma unroll
    for (int i = 0; i < 4; ++i) {
        int row = m0 + ty * 4 + i;
        if (row < M) {
            float4 o;
            o.x = fmaxf(acc[i][0] + b0, 0.f);
            o.y = fmaxf(acc[i][1] + b1, 0.f);
            o.z = fmaxf(acc[i][2] + b2, 0.f);
            o.w = fmaxf(acc[i][3] + b3, 0.f);
            *(float4*)(outp + (size_t)row * DH + n0 + tx * 4) = o;
        }
    }
}

// ---------------- layer-1 transform: z_A, z_B (N x 2) + self term -> out ----------------
__global__ __launch_bounds__(256) void l1_transform_kernel(
    const float* __restrict__ h,
    const float* __restrict__ WzA, const float* __restrict__ WzB,
    const float* __restrict__ Wself, const float* __restrict__ bself,
    float* __restrict__ zA, float* __restrict__ zB, float* __restrict__ outSelf, int n)
{
    int wave = threadIdx.x >> 6;
    int lane = threadIdx.x & 63;
    int node = blockIdx.x * 4 + wave;
    if (node >= n) return;
    const float4 hv  = *(const float4*)(h + (size_t)node * DH + lane * 4);
    const float4 wa0 = *(const float4*)(WzA + lane * 4);
    const float4 wa1 = *(const float4*)(WzA + DH + lane * 4);
    const float4 wb0 = *(const float4*)(WzB + lane * 4);
    const float4 wb1 = *(const float4*)(WzB + DH + lane * 4);
    const float4 ws0 = *(const float4*)(Wself + lane * 4);
    const float4 ws1 = *(const float4*)(Wself + DH + lane * 4);
    float v[6];
    v[0] = hv.x * wa0.x + hv.y * wa0.y + hv.z * wa0.z + hv.w * wa0.w;
    v[1] = hv.x * wa1.x + hv.y * wa1.y + hv.z * wa1.z + hv.w * wa1.w;
    v[2] = hv.x * wb0.x + hv.y * wb0.y + hv.z * wb0.z + hv.w * wb0.w;
    v[3] = hv.x * wb1.x + hv.y * wb1.y + hv.z * wb1.z + hv.w * wb1.w;
    v[4] = hv.x * ws0.x + hv.y * ws0.y + hv.z * ws0.z + hv.w * ws0.w;
    v[5] = hv.x * ws1.x + hv.y * ws1.y + hv.z * ws1.z + hv.w * ws1.w;
#pragma unroll
    for (int m = 32; m > 0; m >>= 1) {
#pragma unroll
        for (int q = 0; q < 6; ++q) v[q] += __shfl_xor(v[q], m, 64);
    }
    if (lane == 0) {
        zA[node * 2]     = v[0];
        zA[node * 2 + 1] = v[1];
        zB[node * 2]     = v[2];
        zB[node * 2 + 1] = v[3];
        outSelf[node * 2]     = v[4] + bself[0];
        outSelf[node * 2 + 1] = v[5] + bself[1];
    }
}

// ---------------- layer-1 aggregate: out += mean_A(zA) + mean_B(zB) ----------------
__global__ __launch_bounds__(256) void l1_agg_kernel(
    const int* __restrict__ rowptr, const int* __restrict__ cnt, const int* __restrict__ col,
    const float* __restrict__ zA, const float* __restrict__ zB,
    int rA, int rB, float* __restrict__ outp, int N, int E)
{
    int i = blockIdx.x * blockDim.x + threadIdx.x;
    if (i >= N) return;
    float ax = 0.f, ay = 0.f;
    {
        int b = rowptr[rA * N + i], c = cnt[rA * N + i];
        const int* cl = col + (size_t)rA * E + b;
        float sx = 0.f, sy = 0.f;
        for (int e = 0; e < c; ++e) {
            int s = cl[e];
            sx += zA[s * 2]; sy += zA[s * 2 + 1];
        }
        float sc = 1.0f / fmaxf((float)c, 1.0f);
        ax += sx * sc; ay += sy * sc;
    }
    {
        int b = rowptr[rB * N + i], c = cnt[rB * N + i];
        const int* cl = col + (size_t)rB * E + b;
        float sx = 0.f, sy = 0.f;
        for (int e = 0; e < c; ++e) {
            int s = cl[e];
            sx += zB[s * 2]; sy += zB[s * 2 + 1];
        }
        float sc = 1.0f / fmaxf((float)c, 1.0f);
        ax += sx * sc; ay += sy * sc;
    }
    outp[i * 2]     += ax;
    outp[i * 2 + 1] += ay;
}

// ---------------- launch ----------------
extern "C" void kernel_launch(void* const* d_in, const int* in_sizes, int n_in,
                              void* d_out, int out_size, void* d_ws, size_t ws_size,
                              hipStream_t stream)
{
    const float* x_tx   = (const float*)d_in[0];
    const float* x_addr = (const float*)d_in[1];
    const int* e_tt = (const int*)d_in[2];
    const int* e_aa = (const int*)d_in[3];
    const int* e_at = (const int*)d_in[4];
    const int* e_ta = (const int*)d_in[5];
    const float* Wl0_tt = (const float*)d_in[6];
    const float* bl0_tt = (const float*)d_in[7];
    const float* Wr0_tt = (const float*)d_in[8];
    const float* Wl0_aa = (const float*)d_in[9];
    const float* bl0_aa = (const float*)d_in[10];
    const float* Wr0_aa = (const float*)d_in[11];
    const float* Wl0_at = (const float*)d_in[12];
    const float* bl0_at = (const float*)d_in[13];
    const float* Wr0_at = (const float*)d_in[14];
    const float* Wl0_ta = (const float*)d_in[15];
    const float* bl0_ta = (const float*)d_in[16];
    const float* Wr0_ta = (const float*)d_in[17];
    const float* Wl1_tt = (const float*)d_in[18];
    const float* bl1_tt = (const float*)d_in[19];
    const float* Wr1_tt = (const float*)d_in[20];
    const float* Wl1_aa = (const float*)d_in[21];
    const float* bl1_aa = (const float*)d_in[22];
    const float* Wr1_aa = (const float*)d_in[23];
    const float* Wl1_at = (const float*)d_in[24];
    const float* bl1_at = (const float*)d_in[25];
    const float* Wr1_at = (const float*)d_in[26];
    const float* Wl1_ta = (const float*)d_in[27];
    const float* bl1_ta = (const float*)d_in[28];
    const float* Wr1_ta = (const float*)d_in[29];

    const int N = in_sizes[0] / DIN;   // 50000
    const int E = in_sizes[2] / 2;     // 400000

    // ---- workspace carve (256B-aligned regions) ----
    size_t off = 0;
    char* base = (char*)d_ws;
    auto alloc = [&](size_t bytes) -> void* {
        void* p = base + off;
        off += (bytes + 255) & ~(size_t)255;
        return p;
    };
    int*   cnt    = (int*)  alloc((size_t)4 * N * 4);
    int*   cursor = (int*)  alloc((size_t)4 * N * 4);
    int*   rowptr = (int*)  alloc((size_t)4 * N * 4);
    int*   col    = (int*)  alloc((size_t)4 * E * 4);
    float* agg    = (float*)alloc((size_t)4 * N * DIN * 4);
    float* h_tx   = (float*)alloc((size_t)N * DH * 4);
    float* h_ad   = (float*)alloc((size_t)N * DH * 4);
    float* z      = (float*)alloc((size_t)4 * N * 2 * 4);
    float* Wr0c   = (float*)alloc((size_t)2 * DH * DIN * 4);
    float* b0c    = (float*)alloc((size_t)2 * DH * 4);
    float* Wr1c   = (float*)alloc((size_t)2 * 2 * DH * 4);
    float* b1c    = (float*)alloc((size_t)2 * 2 * 4);
    (void)ws_size;

    float* out_tx = (float*)d_out;
    float* out_ad = (float*)d_out + (size_t)N * 2;

    // 0. zero cnt + cursor (contiguous: 4N ints each, 4N*4 is a 256 multiple)
    hipMemsetAsync(cnt, 0, (size_t)8 * N * 4, stream);

    // 1. prep folded weights
    prep_kernel<<<(DH * DIN + 255) / 256, 256, 0, stream>>>(
        Wr0_tt, Wr0_aa, Wr0_at, Wr0_ta, bl0_tt, bl0_aa, bl0_at, bl0_ta,
        Wr1_tt, Wr1_aa, Wr1_at, Wr1_ta, bl1_tt, bl1_aa, bl1_at, bl1_ta,
        Wr0c, b0c, Wr1c, b1c);

    // 2. counts
    {
        dim3 g((E + 255) / 256, 4);
        count_kernel<<<g, 256, 0, stream>>>(e_tt, e_aa, e_at, e_ta, cnt, E, N);
    }
    // 3. scan
    scan_kernel<<<4, 1024, 0, stream>>>(cnt, rowptr, N);
    // 4. fill
    {
        dim3 g((E + 255) / 256, 4);
        fill_kernel<<<g, 256, 0, stream>>>(e_tt, e_aa, e_at, e_ta, rowptr, cursor, col, E, N);
    }
    // 5. layer-0 aggregation
    {
        dim3 g((N + 3) / 4, 4);
        agg_kernel<<<g, 256, 0, stream>>>(x_tx, x_addr, rowptr, cnt, col, agg, N, E);
    }
    // 6. layer-0 GEMMs  (relations: 0=tt 1=aa 2=at 3=ta)
    {
        dim3 g((N + 63) / 64, DH / 64);
        gemm0_kernel<<<g, 256, 0, stream>>>(
            agg /*tt*/, agg + (size_t)2 * N * DIN /*at*/, x_tx,
            Wl0_tt, Wl0_at, Wr0c, b0c, h_tx, N);
        gemm0_kernel<<<g, 256, 0, stream>>>(
            agg + (size_t)1 * N * DIN /*aa*/, agg + (size_t)3 * N * DIN /*ta*/, x_addr,
            Wl0_aa, Wl0_ta, Wr0c + DH * DIN, b0c + DH, h_ad, N);
    }
    // 7. layer-1 transforms
    {
        float* z_tt = z;
        float* z_aa = z + (size_t)1 * N * 2;
        float* z_at = z + (size_t)2 * N * 2;
        float* z_ta = z + (size_t)3 * N * 2;
        int g = (N + 3) / 4;
        l1_transform_kernel<<<g, 256, 0, stream>>>(
            h_tx, Wl1_tt, Wl1_ta, Wr1c, b1c, z_tt, z_ta, out_tx, N);
        l1_transform_kernel<<<g, 256, 0, stream>>>(
            h_ad, Wl1_aa, Wl1_at, Wr1c + 2 * DH, b1c + 2, z_aa, z_at, out_ad, N);

        // 8. layer-1 aggregation (CSR walk, adds to self term already in out)
        int g2 = (N + 255) / 256;
        l1_agg_kernel<<<g2, 256, 0, stream>>>(rowptr, cnt, col, z_tt, z_at, 0, 2, out_tx, N, E);
        l1_agg_kernel<<<g2, 256, 0, stream>>>(rowptr, cnt, col, z_aa, z_ta, 1, 3, out_ad, N, E);
    }
}

// Round 2
// 591.104 us; speedup vs baseline: 1.5543x; 1.5543x over previous
//
#include <hip/hip_runtime.h>

// HeteroSAGE on MI355X — round 2: bf16 gathers (quarter-wave), bf16 MFMA GEMM,
// parallel two-pass scan.
//
// Pipeline:
//   0. memset cnt+cursor
//   1. prep: fold Wr/b pairs; convert layer-0 weights to bf16
//   2. convert x_tx/x_addr -> bf16
//   3. count: per-relation in-degree (int atomics)
//   4. scan1/scan2/scan3: exclusive prefix over concatenated [4][N] counts
//      (global positions; relation base r*E is implicit)
//   5. fill: flat CSR column (src) list, 4E ints
//   6. agg:  per-dst mean of bf16 src rows, quarter-wave (4 edges/iter) -> bf16
//   7. gemm0 x2 (MFMA 16x16x32 bf16): h = relu(sum of 3 segs + b), fp32 out
//   8. l1_transform x2: z_r = h@Wl1_r.T (N x 2) fp32, self term -> out
//   9. l1_agg x2: out += mean_r(z) via CSR walk

#define DIN 128
#define DH  256

typedef __attribute__((ext_vector_type(8))) short bf16x8;
typedef __attribute__((ext_vector_type(4))) float f32x4;

__device__ __forceinline__ float bf2f(unsigned int u) {
    return __uint_as_float(u << 16);
}
__device__ __forceinline__ unsigned short f2bf(float f) {
    unsigned int u = __float_as_uint(f);
    u = (u + 0x7fffu + ((u >> 16) & 1u)) >> 16;   // RNE
    return (unsigned short)u;
}

// ---------------- prep: fold self-weights & biases, bf16 weight conversion ----------------
__global__ __launch_bounds__(256) void prep_kernel(
    const float* __restrict__ Wl0_tt, const float* __restrict__ Wl0_aa,
    const float* __restrict__ Wl0_at, const float* __restrict__ Wl0_ta,
    const float* __restrict__ Wr0_tt, const float* __restrict__ Wr0_aa,
    const float* __restrict__ Wr0_at, const float* __restrict__ Wr0_ta,
    const float* __restrict__ bl0_tt, const float* __restrict__ bl0_aa,
    const float* __restrict__ bl0_at, const float* __restrict__ bl0_ta,
    const float* __restrict__ Wr1_tt, const float* __restrict__ Wr1_aa,
    const float* __restrict__ Wr1_at, const float* __restrict__ Wr1_ta,
    const float* __restrict__ bl1_tt, const float* __restrict__ bl1_aa,
    const float* __restrict__ bl1_at, const float* __restrict__ bl1_ta,
    unsigned short* __restrict__ wb_tt, unsigned short* __restrict__ wb_aa,
    unsigned short* __restrict__ wb_at, unsigned short* __restrict__ wb_ta,
    unsigned short* __restrict__ wr0c_tx, unsigned short* __restrict__ wr0c_ad,
    float* __restrict__ b0c,
    float* __restrict__ Wr1c, float* __restrict__ b1c)
{
    int i = blockIdx.x * blockDim.x + threadIdx.x;
    if (i < DH * DIN) {
        wb_tt[i] = f2bf(Wl0_tt[i]);
        wb_aa[i] = f2bf(Wl0_aa[i]);
        wb_at[i] = f2bf(Wl0_at[i]);
        wb_ta[i] = f2bf(Wl0_ta[i]);
        wr0c_tx[i] = f2bf(Wr0_tt[i] + Wr0_at[i]);
        wr0c_ad[i] = f2bf(Wr0_aa[i] + Wr0_ta[i]);
    }
    if (i < DH) {
        b0c[i]      = bl0_tt[i] + bl0_at[i];
        b0c[DH + i] = bl0_aa[i] + bl0_ta[i];
    }
    if (i < 2 * DH) {
        Wr1c[i]          = Wr1_tt[i] + Wr1_at[i];
        Wr1c[2 * DH + i] = Wr1_aa[i] + Wr1_ta[i];
    }
    if (i < 2) {
        b1c[i]     = bl1_tt[i] + bl1_at[i];
        b1c[2 + i] = bl1_aa[i] + bl1_ta[i];
    }
}

// ---------------- feature conversion fp32 -> bf16 ----------------
__global__ __launch_bounds__(256) void convert_kernel(
    const float* __restrict__ in, unsigned short* __restrict__ outp, int n8)
{
    int i = blockIdx.x * blockDim.x + threadIdx.x;
    if (i >= n8) return;
    const float4* p = (const float4*)(in + (size_t)i * 8);
    float4 a = p[0], b = p[1];
    uint4 o;
    o.x = (unsigned)f2bf(a.x) | ((unsigned)f2bf(a.y) << 16);
    o.y = (unsigned)f2bf(a.z) | ((unsigned)f2bf(a.w) << 16);
    o.z = (unsigned)f2bf(b.x) | ((unsigned)f2bf(b.y) << 16);
    o.w = (unsigned)f2bf(b.z) | ((unsigned)f2bf(b.w) << 16);
    *(uint4*)(outp + (size_t)i * 8) = o;
}

// ---------------- CSR build ----------------
__global__ __launch_bounds__(256) void count_kernel(
    const int* __restrict__ e0, const int* __restrict__ e1,
    const int* __restrict__ e2, const int* __restrict__ e3,
    int* __restrict__ cnt, int E, int N)
{
    int r = blockIdx.y;
    const int* e = (r == 0) ? e0 : (r == 1) ? e1 : (r == 2) ? e2 : e3;
    int i = blockIdx.x * blockDim.x + threadIdx.x;
    if (i < E) {
        int d = e[E + i];
        atomicAdd(&cnt[r * N + d], 1);
    }
}

// two-pass scan over n=4N concatenated counts -> global exclusive prefix
__global__ __launch_bounds__(1024) void scan1_kernel(
    const int* __restrict__ cnt, int* __restrict__ excl, int* __restrict__ bsums, int n)
{
    __shared__ int sdata[1024];
    int i = blockIdx.x * 1024 + threadIdx.x;
    int v = (i < n) ? cnt[i] : 0;
    sdata[threadIdx.x] = v;
    __syncthreads();
    for (int off = 1; off < 1024; off <<= 1) {
        int t = (threadIdx.x >= off) ? sdata[threadIdx.x - off] : 0;
        __syncthreads();
        sdata[threadIdx.x] += t;
        __syncthreads();
    }
    if (i < n) excl[i] = sdata[threadIdx.x] - v;
    if (threadIdx.x == 1023) bsums[blockIdx.x] = sdata[1023];
}

__global__ __launch_bounds__(256) void scan2_kernel(int* __restrict__ bsums, int nb)
{
    __shared__ int sdata[256];
    int v = (threadIdx.x < nb) ? bsums[threadIdx.x] : 0;
    sdata[threadIdx.x] = v;
    __syncthreads();
    for (int off = 1; off < 256; off <<= 1) {
        int t = (threadIdx.x >= off) ? sdata[threadIdx.x - off] : 0;
        __syncthreads();
        sdata[threadIdx.x] += t;
        __syncthreads();
    }
    if (threadIdx.x < nb) bsums[threadIdx.x] = sdata[threadIdx.x] - v;
}

__global__ __launch_bounds__(1024) void scan3_kernel(
    int* __restrict__ excl, const int* __restrict__ bsums, int n)
{
    int i = blockIdx.x * 1024 + threadIdx.x;
    if (i < n) excl[i] += bsums[blockIdx.x];
}

__global__ __launch_bounds__(256) void fill_kernel(
    const int* __restrict__ e0, const int* __restrict__ e1,
    const int* __restrict__ e2, const int* __restrict__ e3,
    const int* __restrict__ rowptr, int* __restrict__ cursor,
    int* __restrict__ col, int E, int N)
{
    int r = blockIdx.y;
    const int* e = (r == 0) ? e0 : (r == 1) ? e1 : (r == 2) ? e2 : e3;
    int i = blockIdx.x * blockDim.x + threadIdx.x;
    if (i < E) {
        int s = e[i];
        int d = e[E + i];
        int pos = rowptr[r * N + d] + atomicAdd(&cursor[r * N + d], 1);
        col[pos] = s;                  // rowptr is a GLOBAL position (r*E baked in)
    }
}

// ---------------- layer-0 mean aggregation: quarter-wave, bf16 ----------------
__global__ __launch_bounds__(256) void agg_kernel(
    const unsigned short* __restrict__ xb_tx, const unsigned short* __restrict__ xb_ad,
    const int* __restrict__ rowptr, const int* __restrict__ cnt,
    const int* __restrict__ col, unsigned short* __restrict__ aggb, int N)
{
    int r = blockIdx.y;                        // 0=tt 1=aa 2=at 3=ta
    const unsigned short* xs = (r == 0 || r == 3) ? xb_tx : xb_ad;
    int wave = threadIdx.x >> 6;
    int l    = threadIdx.x & 63;
    int node = blockIdx.x * 4 + wave;
    if (node >= N) return;
    int base = rowptr[r * N + node];
    int c    = cnt[r * N + node];
    const int* cl = col + base;
    int q = l >> 4;                            // quarter: which edge of a group of 4
    int d = l & 15;                            // dim slot: 8 bf16 at d*8
    float acc[8] = {};
    for (int e0 = 0; e0 < c; e0 += 4) {
        int e = e0 + q;
        if (e < c) {
            int s = cl[e];
            uint4 u = *(const uint4*)(xs + (size_t)s * DIN + d * 8);
            acc[0] += bf2f(u.x & 0xffffu); acc[1] += bf2f(u.x >> 16);
            acc[2] += bf2f(u.y & 0xffffu); acc[3] += bf2f(u.y >> 16);
            acc[4] += bf2f(u.z & 0xffffu); acc[5] += bf2f(u.z >> 16);
            acc[6] += bf2f(u.w & 0xffffu); acc[7] += bf2f(u.w >> 16);
        }
    }
#pragma unroll
    for (int j = 0; j < 8; ++j) {
        acc[j] += __shfl_xor(acc[j], 16, 64);
        acc[j] += __shfl_xor(acc[j], 32, 64);
    }
    if (q == 0) {
        float sc = 1.0f / fmaxf((float)c, 1.0f);
        uint4 o;
        o.x = (unsigned)f2bf(acc[0] * sc) | ((unsigned)f2bf(acc[1] * sc) << 16);
        o.y = (unsigned)f2bf(acc[2] * sc) | ((unsigned)f2bf(acc[3] * sc) << 16);
        o.z = (unsigned)f2bf(acc[4] * sc) | ((unsigned)f2bf(acc[5] * sc) << 16);
        o.w = (unsigned)f2bf(acc[6] * sc) | ((unsigned)f2bf(acc[7] * sc) << 16);
        *(uint4*)(aggb + ((size_t)r * N + node) * DIN + d * 8) = o;
    }
}

// ---------------- layer-0 GEMM via MFMA 16x16x32 bf16 ----------------
// h[row][col] = relu( sum_seg A_seg[row]@W_seg[col]^T + bias[col] ), fp32 out.
// Block: 256 thr = 4 waves; block tile M=32 (shared), each wave owns 64 cols.
__global__ __launch_bounds__(256) void gemm0_mfma_kernel(
    const unsigned short* __restrict__ A0, const unsigned short* __restrict__ A1,
    const unsigned short* __restrict__ A2,
    const unsigned short* __restrict__ W0, const unsigned short* __restrict__ W1,
    const unsigned short* __restrict__ W2,
    const float* __restrict__ bias, float* __restrict__ h, int M)
{
    int wv = threadIdx.x >> 6;
    int l  = threadIdx.x & 63;
    int lr = l & 15;
    int q  = l >> 4;
    int m0 = blockIdx.x * 32;
    int n0 = wv * 64;

    f32x4 acc[2][4] = {};
    const unsigned short* As[3] = {A0, A1, A2};
    const unsigned short* Ws[3] = {W0, W1, W2};

    int ra0 = m0 + lr;       if (ra0 >= M) ra0 = M - 1;
    int ra1 = m0 + 16 + lr;  if (ra1 >= M) ra1 = M - 1;

    for (int seg = 0; seg < 3; ++seg) {
        const unsigned short* A = As[seg];
        const unsigned short* W = Ws[seg];
        const unsigned short* pa0 = A + (size_t)ra0 * DIN + q * 8;
        const unsigned short* pa1 = A + (size_t)ra1 * DIN + q * 8;
        const unsigned short* pb0 = W + (size_t)(n0 + lr) * DIN + q * 8;
        const unsigned short* pb1 = W + (size_t)(n0 + 16 + lr) * DIN + q * 8;
        const unsigned short* pb2 = W + (size_t)(n0 + 32 + lr) * DIN + q * 8;
        const unsigned short* pb3 = W + (size_t)(n0 + 48 + lr) * DIN + q * 8;
#pragma unroll
        for (int k = 0; k < DIN; k += 32) {
            bf16x8 a0 = *(const bf16x8*)(pa0 + k);
            bf16x8 a1 = *(const bf16x8*)(pa1 + k);
            bf16x8 b0 = *(const bf16x8*)(pb0 + k);
            bf16x8 b1 = *(const bf16x8*)(pb1 + k);
            bf16x8 b2 = *(const bf16x8*)(pb2 + k);
            bf16x8 b3 = *(const bf16x8*)(pb3 + k);
            acc[0][0] = __builtin_amdgcn_mfma_f32_16x16x32_bf16(a0, b0, acc[0][0], 0, 0, 0);
            acc[0][1] = __builtin_amdgcn_mfma_f32_16x16x32_bf16(a0, b1, acc[0][1], 0, 0, 0);
            acc[0][2] = __builtin_amdgcn_mfma_f32_16x16x32_bf16(a0, b2, acc[0][2], 0, 0, 0);
            acc[0][3] = __builtin_amdgcn_mfma_f32_16x16x32_bf16(a0, b3, acc[0][3], 0, 0, 0);
            acc[1][0] = __builtin_amdgcn_mfma_f32_16x16x32_bf16(a1, b0, acc[1][0], 0, 0, 0);
            acc[1][1] = __builtin_amdgcn_mfma_f32_16x16x32_bf16(a1, b1, acc[1][1], 0, 0, 0);
            acc[1][2] = __builtin_amdgcn_mfma_f32_16x16x32_bf16(a1, b2, acc[1][2], 0, 0, 0);
            acc[1][3] = __builtin_amdgcn_mfma_f32_16x16x32_bf16(a1, b3, acc[1][3], 0, 0, 0);
        }
    }

#pragma unroll
    for (int mt = 0; mt < 2; ++mt) {
#pragma unroll
        for (int nt = 0; nt < 4; ++nt) {
            int colc = n0 + nt * 16 + lr;
            float b = bias[colc];
#pragma unroll
            for (int rr = 0; rr < 4; ++rr) {
                int row = m0 + mt * 16 + q * 4 + rr;
                if (row < M)
                    h[(size_t)row * DH + colc] = fmaxf(acc[mt][nt][rr] + b, 0.f);
            }
        }
    }
}

// ---------------- layer-1 transform: z_A, z_B (N x 2) + self term -> out ----------------
__global__ __launch_bounds__(256) void l1_transform_kernel(
    const float* __restrict__ h,
    const float* __restrict__ WzA, const float* __restrict__ WzB,
    const float* __restrict__ Wself, const float* __restrict__ bself,
    float* __restrict__ zA, float* __restrict__ zB, float* __restrict__ outSelf, int n)
{
    int wave = threadIdx.x >> 6;
    int lane = threadIdx.x & 63;
    int node = blockIdx.x * 4 + wave;
    if (node >= n) return;
    const float4 hv  = *(const float4*)(h + (size_t)node * DH + lane * 4);
    const float4 wa0 = *(const float4*)(WzA + lane * 4);
    const float4 wa1 = *(const float4*)(WzA + DH + lane * 4);
    const float4 wb0 = *(const float4*)(WzB + lane * 4);
    const float4 wb1 = *(const float4*)(WzB + DH + lane * 4);
    const float4 ws0 = *(const float4*)(Wself + lane * 4);
    const float4 ws1 = *(const float4*)(Wself + DH + lane * 4);
    float v[6];
    v[0] = hv.x * wa0.x + hv.y * wa0.y + hv.z * wa0.z + hv.w * wa0.w;
    v[1] = hv.x * wa1.x + hv.y * wa1.y + hv.z * wa1.z + hv.w * wa1.w;
    v[2] = hv.x * wb0.x + hv.y * wb0.y + hv.z * wb0.z + hv.w * wb0.w;
    v[3] = hv.x * wb1.x + hv.y * wb1.y + hv.z * wb1.z + hv.w * wb1.w;
    v[4] = hv.x * ws0.x + hv.y * ws0.y + hv.z * ws0.z + hv.w * ws0.w;
    v[5] = hv.x * ws1.x + hv.y * ws1.y + hv.z * ws1.z + hv.w * ws1.w;
#pragma unroll
    for (int m = 32; m > 0; m >>= 1) {
#pragma unroll
        for (int qq = 0; qq < 6; ++qq) v[qq] += __shfl_xor(v[qq], m, 64);
    }
    if (lane == 0) {
        zA[node * 2]     = v[0];
        zA[node * 2 + 1] = v[1];
        zB[node * 2]     = v[2];
        zB[node * 2 + 1] = v[3];
        outSelf[node * 2]     = v[4] + bself[0];
        outSelf[node * 2 + 1] = v[5] + bself[1];
    }
}

// ---------------- layer-1 aggregate: out += mean_A(zA) + mean_B(zB) ----------------
__global__ __launch_bounds__(256) void l1_agg_kernel(
    const int* __restrict__ rowptr, const int* __restrict__ cnt, const int* __restrict__ col,
    const float* __restrict__ zA, const float* __restrict__ zB,
    int rA, int rB, float* __restrict__ outp, int N)
{
    int i = blockIdx.x * blockDim.x + threadIdx.x;
    if (i >= N) return;
    float ax = 0.f, ay = 0.f;
    {
        int b = rowptr[rA * N + i], c = cnt[rA * N + i];
        const int* cl = col + b;
        float sx = 0.f, sy = 0.f;
        for (int e = 0; e < c; ++e) {
            int s = cl[e];
            sx += zA[s * 2]; sy += zA[s * 2 + 1];
        }
        float sc = 1.0f / fmaxf((float)c, 1.0f);
        ax += sx * sc; ay += sy * sc;
    }
    {
        int b = rowptr[rB * N + i], c = cnt[rB * N + i];
        const int* cl = col + b;
        float sx = 0.f, sy = 0.f;
        for (int e = 0; e < c; ++e) {
            int s = cl[e];
            sx += zB[s * 2]; sy += zB[s * 2 + 1];
        }
        float sc = 1.0f / fmaxf((float)c, 1.0f);
        ax += sx * sc; ay += sy * sc;
    }
    outp[i * 2]     += ax;
    outp[i * 2 + 1] += ay;
}

// ---------------- launch ----------------
extern "C" void kernel_launch(void* const* d_in, const int* in_sizes, int n_in,
                              void* d_out, int out_size, void* d_ws, size_t ws_size,
                              hipStream_t stream)
{
    const float* x_tx   = (const float*)d_in[0];
    const float* x_addr = (const float*)d_in[1];
    const int* e_tt = (const int*)d_in[2];
    const int* e_aa = (const int*)d_in[3];
    const int* e_at = (const int*)d_in[4];
    const int* e_ta = (const int*)d_in[5];
    const float* Wl0_tt = (const float*)d_in[6];
    const float* bl0_tt = (const float*)d_in[7];
    const float* Wr0_tt = (const float*)d_in[8];
    const float* Wl0_aa = (const float*)d_in[9];
    const float* bl0_aa = (const float*)d_in[10];
    const float* Wr0_aa = (const float*)d_in[11];
    const float* Wl0_at = (const float*)d_in[12];
    const float* bl0_at = (const float*)d_in[13];
    const float* Wr0_at = (const float*)d_in[14];
    const float* Wl0_ta = (const float*)d_in[15];
    const float* bl0_ta = (const float*)d_in[16];
    const float* Wr0_ta = (const float*)d_in[17];
    const float* Wl1_tt = (const float*)d_in[18];
    const float* bl1_tt = (const float*)d_in[19];
    const float* Wr1_tt = (const float*)d_in[20];
    const float* Wl1_aa = (const float*)d_in[21];
    const float* bl1_aa = (const float*)d_in[22];
    const float* Wr1_aa = (const float*)d_in[23];
    const float* Wl1_at = (const float*)d_in[24];
    const float* bl1_at = (const float*)d_in[25];
    const float* Wr1_at = (const float*)d_in[26];
    const float* Wl1_ta = (const float*)d_in[27];
    const float* bl1_ta = (const float*)d_in[28];
    const float* Wr1_ta = (const float*)d_in[29];

    const int N = in_sizes[0] / DIN;   // 50000
    const int E = in_sizes[2] / 2;     // 400000

    size_t off = 0;
    char* base = (char*)d_ws;
    auto alloc = [&](size_t bytes) -> void* {
        void* p = base + off;
        off += (bytes + 255) & ~(size_t)255;
        return p;
    };
    int*   cnt    = (int*)  alloc((size_t)4 * N * 4);
    int*   cursor = (int*)  alloc((size_t)4 * N * 4);
    int*   rowptr = (int*)  alloc((size_t)4 * N * 4);     // global exclusive prefix
    int*   bsums  = (int*)  alloc((size_t)256 * 4);
    int*   col    = (int*)  alloc((size_t)4 * E * 4);     // flat, global positions
    unsigned short* xb_tx = (unsigned short*)alloc((size_t)N * DIN * 2);
    unsigned short* xb_ad = (unsigned short*)alloc((size_t)N * DIN * 2);
    unsigned short* aggb  = (unsigned short*)alloc((size_t)4 * N * DIN * 2);
    float* h_tx   = (float*)alloc((size_t)N * DH * 4);
    float* h_ad   = (float*)alloc((size_t)N * DH * 4);
    float* z      = (float*)alloc((size_t)4 * N * 2 * 4);
    unsigned short* wb_tt  = (unsigned short*)alloc((size_t)DH * DIN * 2);
    unsigned short* wb_aa  = (unsigned short*)alloc((size_t)DH * DIN * 2);
    unsigned short* wb_at  = (unsigned short*)alloc((size_t)DH * DIN * 2);
    unsigned short* wb_ta  = (unsigned short*)alloc((size_t)DH * DIN * 2);
    unsigned short* wr0c_tx = (unsigned short*)alloc((size_t)DH * DIN * 2);
    unsigned short* wr0c_ad = (unsigned short*)alloc((size_t)DH * DIN * 2);
    float* b0c    = (float*)alloc((size_t)2 * DH * 4);
    float* Wr1c   = (float*)alloc((size_t)2 * 2 * DH * 4);
    float* b1c    = (float*)alloc((size_t)2 * 2 * 4);
    (void)ws_size;

    float* out_tx = (float*)d_out;
    float* out_ad = (float*)d_out + (size_t)N * 2;

    const int n4 = 4 * N;

    // 0. zero cnt + cursor (contiguous regions)
    hipMemsetAsync(cnt, 0, (size_t)8 * N * 4, stream);

    // 1. prep folded/converted weights
    prep_kernel<<<(DH * DIN + 255) / 256, 256, 0, stream>>>(
        Wl0_tt, Wl0_aa, Wl0_at, Wl0_ta,
        Wr0_tt, Wr0_aa, Wr0_at, Wr0_ta,
        bl0_tt, bl0_aa, bl0_at, bl0_ta,
        Wr1_tt, Wr1_aa, Wr1_at, Wr1_ta,
        bl1_tt, bl1_aa, bl1_at, bl1_ta,
        wb_tt, wb_aa, wb_at, wb_ta, wr0c_tx, wr0c_ad, b0c, Wr1c, b1c);

    // 2. feature conversion
    {
        int n8 = N * DIN / 8;
        convert_kernel<<<(n8 + 255) / 256, 256, 0, stream>>>(x_tx, xb_tx, n8);
        convert_kernel<<<(n8 + 255) / 256, 256, 0, stream>>>(x_addr, xb_ad, n8);
    }

    // 3. counts
    {
        dim3 g((E + 255) / 256, 4);
        count_kernel<<<g, 256, 0, stream>>>(e_tt, e_aa, e_at, e_ta, cnt, E, N);
    }
    // 4. scan (two-pass)
    {
        int nb = (n4 + 1023) / 1024;     // 196
        scan1_kernel<<<nb, 1024, 0, stream>>>(cnt, rowptr, bsums, n4);
        scan2_kernel<<<1, 256, 0, stream>>>(bsums, nb);
        scan3_kernel<<<nb, 1024, 0, stream>>>(rowptr, bsums, n4);
    }
    // 5. fill
    {
        dim3 g((E + 255) / 256, 4);
        fill_kernel<<<g, 256, 0, stream>>>(e_tt, e_aa, e_at, e_ta, rowptr, cursor, col, E, N);
    }
    // 6. layer-0 aggregation (bf16, quarter-wave)
    {
        dim3 g((N + 3) / 4, 4);
        agg_kernel<<<g, 256, 0, stream>>>(xb_tx, xb_ad, rowptr, cnt, col, aggb, N);
    }
    // 7. layer-0 GEMMs (MFMA)
    {
        int g = (N + 31) / 32;
        gemm0_mfma_kernel<<<g, 256, 0, stream>>>(
            aggb /*tt*/, aggb + (size_t)2 * N * DIN /*at*/, xb_tx,
            wb_tt, wb_at, wr0c_tx, b0c, h_tx, N);
        gemm0_mfma_kernel<<<g, 256, 0, stream>>>(
            aggb + (size_t)1 * N * DIN /*aa*/, aggb + (size_t)3 * N * DIN /*ta*/, xb_ad,
            wb_aa, wb_ta, wr0c_ad, b0c + DH, h_ad, N);
    }
    // 8. layer-1 transforms + 9. aggregation
    {
        float* z_tt = z;
        float* z_aa = z + (size_t)1 * N * 2;
        float* z_at = z + (size_t)2 * N * 2;
        float* z_ta = z + (size_t)3 * N * 2;
        int g = (N + 3) / 4;
        l1_transform_kernel<<<g, 256, 0, stream>>>(
            h_tx, Wl1_tt, Wl1_ta, Wr1c, b1c, z_tt, z_ta, out_tx, N);
        l1_transform_kernel<<<g, 256, 0, stream>>>(
            h_ad, Wl1_aa, Wl1_at, Wr1c + 2 * DH, b1c + 2, z_aa, z_at, out_ad, N);

        int g2 = (N + 255) / 256;
        l1_agg_kernel<<<g2, 256, 0, stream>>>(rowptr, cnt, col, z_tt, z_at, 0, 2, out_tx, N);
        l1_agg_kernel<<<g2, 256, 0, stream>>>(rowptr, cnt, col, z_aa, z_ta, 1, 3, out_ad, N);
    }
}

// Round 3
// 565.965 us; speedup vs baseline: 1.6234x; 1.0444x over previous
//
#include <hip/hip_runtime.h>

// HeteroSAGE on MI355X — round 3: fused gather+MFMA layer-0, bf16 h,
// lookback scan, launch consolidation (8 graph nodes).
//
// Pipeline:
//   1. setup: zero cnt/cursor/desc, convert x->bf16, fold/convert weights
//   2. count: per-relation in-degree (int atomics)
//   3. scan: single-kernel decoupled-lookback exclusive prefix (ticket-ordered)
//   4. fill: flat CSR column list (global positions, r*E baked in)
//   5. fused0 (grid.y=2 dst types): per 32-node tile, gather+mean 2 relations
//      into LDS (bf16, stride 136), MFMA 3 segments (relA, relB, self),
//      relu+bias -> h bf16
//   6. l1_transform (y=2): z_r = h@Wl1_r.T (N x 2) fp32, self term -> out
//   7. l1_agg (y=2): out += mean_r(z) via CSR walk

#define DIN 128
#define DH  256
#define LDSW 136   // LDS row stride in shorts: 68 dwords -> uniform bank load for b128

typedef __attribute__((ext_vector_type(8))) short bf16x8;
typedef __attribute__((ext_vector_type(4))) float f32x4;

__device__ __forceinline__ float bf2f(unsigned int u) {
    return __uint_as_float(u << 16);
}
__device__ __forceinline__ unsigned short f2bf(float f) {
    unsigned int u = __float_as_uint(f);
    u = (u + 0x7fffu + ((u >> 16) & 1u)) >> 16;   // RNE
    return (unsigned short)u;
}

// ---------------- setup: zero counters, convert features, fold weights ----------------
__global__ __launch_bounds__(256) void setup_kernel(
    const float* __restrict__ x_tx, const float* __restrict__ x_addr,
    const float* __restrict__ Wl0_tt, const float* __restrict__ Wl0_aa,
    const float* __restrict__ Wl0_at, const float* __restrict__ Wl0_ta,
    const float* __restrict__ Wr0_tt, const float* __restrict__ Wr0_aa,
    const float* __restrict__ Wr0_at, const float* __restrict__ Wr0_ta,
    const float* __restrict__ bl0_tt, const float* __restrict__ bl0_aa,
    const float* __restrict__ bl0_at, const float* __restrict__ bl0_ta,
    const float* __restrict__ Wr1_tt, const float* __restrict__ Wr1_aa,
    const float* __restrict__ Wr1_at, const float* __restrict__ Wr1_ta,
    const float* __restrict__ bl1_tt, const float* __restrict__ bl1_aa,
    const float* __restrict__ bl1_at, const float* __restrict__ bl1_ta,
    unsigned short* __restrict__ xb_tx, unsigned short* __restrict__ xb_ad,
    int* __restrict__ cntcur, unsigned long long* __restrict__ desc,
    unsigned short* __restrict__ wb_tt, unsigned short* __restrict__ wb_aa,
    unsigned short* __restrict__ wb_at, unsigned short* __restrict__ wb_ta,
    unsigned short* __restrict__ wr0c_tx, unsigned short* __restrict__ wr0c_ad,
    float* __restrict__ b0c, float* __restrict__ Wr1c, float* __restrict__ b1c,
    int N)
{
    int i = blockIdx.x * blockDim.x + threadIdx.x;
    int nconv = N * DIN / 8;                 // 800000
    if (i < nconv) {
        {
            const float4* p = (const float4*)(x_tx + (size_t)i * 8);
            float4 a = p[0], b = p[1];
            uint4 o;
            o.x = (unsigned)f2bf(a.x) | ((unsigned)f2bf(a.y) << 16);
            o.y = (unsigned)f2bf(a.z) | ((unsigned)f2bf(a.w) << 16);
            o.z = (unsigned)f2bf(b.x) | ((unsigned)f2bf(b.y) << 16);
            o.w = (unsigned)f2bf(b.z) | ((unsigned)f2bf(b.w) << 16);
            *(uint4*)(xb_tx + (size_t)i * 8) = o;
        }
        {
            const float4* p = (const float4*)(x_addr + (size_t)i * 8);
            float4 a = p[0], b = p[1];
            uint4 o;
            o.x = (unsigned)f2bf(a.x) | ((unsigned)f2bf(a.y) << 16);
            o.y = (unsigned)f2bf(a.z) | ((unsigned)f2bf(a.w) << 16);
            o.z = (unsigned)f2bf(b.x) | ((unsigned)f2bf(b.y) << 16);
            o.w = (unsigned)f2bf(b.z) | ((unsigned)f2bf(b.w) << 16);
            *(uint4*)(xb_ad + (size_t)i * 8) = o;
        }
    }
    if (i < 2 * N)                            // 8N ints = 2N int4 (cnt + cursor)
        ((int4*)cntcur)[i] = make_int4(0, 0, 0, 0);
    if (i < 257) desc[i] = 0ULL;              // lookback descriptors + ticket
    if (i < DH * DIN) {
        wb_tt[i] = f2bf(Wl0_tt[i]);
        wb_aa[i] = f2bf(Wl0_aa[i]);
        wb_at[i] = f2bf(Wl0_at[i]);
        wb_ta[i] = f2bf(Wl0_ta[i]);
        wr0c_tx[i] = f2bf(Wr0_tt[i] + Wr0_at[i]);
        wr0c_ad[i] = f2bf(Wr0_aa[i] + Wr0_ta[i]);
    }
    if (i < DH) {
        b0c[i]      = bl0_tt[i] + bl0_at[i];
        b0c[DH + i] = bl0_aa[i] + bl0_ta[i];
    }
    if (i < 2 * DH) {
        Wr1c[i]          = Wr1_tt[i] + Wr1_at[i];
        Wr1c[2 * DH + i] = Wr1_aa[i] + Wr1_ta[i];
    }
    if (i < 2) {
        b1c[i]     = bl1_tt[i] + bl1_at[i];
        b1c[2 + i] = bl1_aa[i] + bl1_ta[i];
    }
}

// ---------------- CSR build ----------------
__global__ __launch_bounds__(256) void count_kernel(
    const int* __restrict__ e0, const int* __restrict__ e1,
    const int* __restrict__ e2, const int* __restrict__ e3,
    int* __restrict__ cnt, int E, int N)
{
    int r = blockIdx.y;
    const int* e = (r == 0) ? e0 : (r == 1) ? e1 : (r == 2) ? e2 : e3;
    int i = blockIdx.x * blockDim.x + threadIdx.x;
    if (i < E) {
        int d = e[E + i];
        atomicAdd(&cnt[r * N + d], 1);
    }
}

// single-kernel decoupled-lookback exclusive scan; segment order from ticket
// (desc[256]) so predecessors are always already running -> no deadlock.
__global__ __launch_bounds__(1024) void scan_kernel(
    const int* __restrict__ cnt, int* __restrict__ excl,
    unsigned long long* __restrict__ desc, int n)
{
    __shared__ int sdata[1024];
    __shared__ int sseg;
    __shared__ int sprev;
    if (threadIdx.x == 0) sseg = (int)atomicAdd(&desc[256], 1ULL);
    __syncthreads();
    int seg = sseg;
    int i = seg * 1024 + threadIdx.x;
    int v = (i < n) ? cnt[i] : 0;
    sdata[threadIdx.x] = v;
    __syncthreads();
    for (int off = 1; off < 1024; off <<= 1) {
        int t = (threadIdx.x >= off) ? sdata[threadIdx.x - off] : 0;
        __syncthreads();
        sdata[threadIdx.x] += t;
        __syncthreads();
    }
    if (threadIdx.x == 0) {
        int total = sdata[1023];
        int prev = 0;
        if (seg == 0) {
            atomicExch(&desc[0], ((unsigned long long)(unsigned)total << 2) | 2ULL);
        } else {
            atomicExch(&desc[seg], ((unsigned long long)(unsigned)total << 2) | 1ULL);
            int j = seg - 1;
            for (;;) {
                unsigned long long d = atomicAdd(&desc[j], 0ULL);   // device-scope read
                unsigned st = (unsigned)(d & 3ULL);
                if (st == 0u) continue;
                prev += (int)(d >> 2);
                if (st == 2u) break;
                --j;
            }
            atomicExch(&desc[seg],
                       ((unsigned long long)(unsigned)(prev + total) << 2) | 2ULL);
        }
        sprev = prev;
    }
    __syncthreads();
    if (i < n) excl[i] = sprev + sdata[threadIdx.x] - v;
}

__global__ __launch_bounds__(256) void fill_kernel(
    const int* __restrict__ e0, const int* __restrict__ e1,
    const int* __restrict__ e2, const int* __restrict__ e3,
    const int* __restrict__ rowptr, int* __restrict__ cursor,
    int* __restrict__ col, int E, int N)
{
    int r = blockIdx.y;
    const int* e = (r == 0) ? e0 : (r == 1) ? e1 : (r == 2) ? e2 : e3;
    int i = blockIdx.x * blockDim.x + threadIdx.x;
    if (i < E) {
        int s = e[i];
        int d = e[E + i];
        int pos = rowptr[r * N + d] + atomicAdd(&cursor[r * N + d], 1);
        col[pos] = s;                  // global position (r*E baked in)
    }
}

// ---------------- fused layer-0: gather+mean into LDS, then MFMA ----------------
// blockIdx.y = dst type (0=tx, 1=addr). Per block: 32 dst nodes.
// LDS rows 0..31 = mean over relA, rows 32..63 = mean over relB (bf16).
// h = relu(meanA@W0^T + meanB@W1^T + x_self@W2^T + bias), stored bf16.
__global__ __launch_bounds__(256) void fused0_kernel(
    const unsigned short* __restrict__ xb_tx, const unsigned short* __restrict__ xb_ad,
    const int* __restrict__ rowptr, const int* __restrict__ cnt,
    const int* __restrict__ col,
    const unsigned short* __restrict__ wb_tt, const unsigned short* __restrict__ wb_at,
    const unsigned short* __restrict__ wr0c_tx,
    const unsigned short* __restrict__ wb_aa, const unsigned short* __restrict__ wb_ta,
    const unsigned short* __restrict__ wr0c_ad,
    const float* __restrict__ b0c,
    unsigned short* __restrict__ h_tx, unsigned short* __restrict__ h_ad, int N)
{
    __shared__ unsigned short lds[64 * LDSW];
    const int type = blockIdx.y;
    const unsigned short* srcA  = (type == 0) ? xb_tx : xb_ad;   // tt / aa
    const unsigned short* srcB  = (type == 0) ? xb_ad : xb_tx;   // at / ta
    const unsigned short* xself = (type == 0) ? xb_tx : xb_ad;
    const int relA = (type == 0) ? 0 : 1;
    const int relB = (type == 0) ? 2 : 3;
    const unsigned short* W0 = (type == 0) ? wb_tt  : wb_aa;
    const unsigned short* W1 = (type == 0) ? wb_at  : wb_ta;
    const unsigned short* W2 = (type == 0) ? wr0c_tx : wr0c_ad;
    const float* bias = b0c + type * DH;
    unsigned short* h = (type == 0) ? h_tx : h_ad;

    const int wv = threadIdx.x >> 6;
    const int l  = threadIdx.x & 63;
    const int q  = l >> 4;
    const int lr = l & 15;
    const int m0 = blockIdx.x * 32;

    // ---- gather phase: 16 (node,rel) tasks per wave ----
    for (int j = 0; j < 16; ++j) {
        int t = wv * 16 + j;
        int node = m0 + (t & 31);
        int rel = (t < 32) ? relA : relB;
        const unsigned short* xs = (t < 32) ? srcA : srcB;
        float acc[8] = {};
        int c = 0;
        if (node < N) {
            int bse = rowptr[rel * N + node];
            c = cnt[rel * N + node];
            const int* cl = col + bse;
            for (int e0 = 0; e0 < c; e0 += 4) {
                int e = e0 + q;
                if (e < c) {
                    int s = cl[e];
                    uint4 u = *(const uint4*)(xs + (size_t)s * DIN + lr * 8);
                    acc[0] += bf2f(u.x & 0xffffu); acc[1] += bf2f(u.x >> 16);
                    acc[2] += bf2f(u.y & 0xffffu); acc[3] += bf2f(u.y >> 16);
                    acc[4] += bf2f(u.z & 0xffffu); acc[5] += bf2f(u.z >> 16);
                    acc[6] += bf2f(u.w & 0xffffu); acc[7] += bf2f(u.w >> 16);
                }
            }
        }
#pragma unroll
        for (int jj = 0; jj < 8; ++jj) {
            acc[jj] += __shfl_xor(acc[jj], 16, 64);
            acc[jj] += __shfl_xor(acc[jj], 32, 64);
        }
        if (q == 0) {
            float sc = 1.0f / fmaxf((float)c, 1.0f);
            uint4 o;
            o.x = (unsigned)f2bf(acc[0] * sc) | ((unsigned)f2bf(acc[1] * sc) << 16);
            o.y = (unsigned)f2bf(acc[2] * sc) | ((unsigned)f2bf(acc[3] * sc) << 16);
            o.z = (unsigned)f2bf(acc[4] * sc) | ((unsigned)f2bf(acc[5] * sc) << 16);
            o.w = (unsigned)f2bf(acc[6] * sc) | ((unsigned)f2bf(acc[7] * sc) << 16);
            *(uint4*)&lds[t * LDSW + lr * 8] = o;
        }
    }
    __syncthreads();

    // ---- MFMA phase: wave wv owns cols n0..n0+63 ----
    const int n0 = wv * 64;
    f32x4 accm[2][4] = {};
#pragma unroll
    for (int seg = 0; seg < 2; ++seg) {
        const unsigned short* Wg = (seg == 0) ? W0 : W1;
        const unsigned short* la0 = &lds[(seg * 32 + lr) * LDSW + q * 8];
        const unsigned short* la1 = &lds[(seg * 32 + 16 + lr) * LDSW + q * 8];
        const unsigned short* pb0 = Wg + (size_t)(n0 + lr) * DIN + q * 8;
        const unsigned short* pb1 = Wg + (size_t)(n0 + 16 + lr) * DIN + q * 8;
        const unsigned short* pb2 = Wg + (size_t)(n0 + 32 + lr) * DIN + q * 8;
        const unsigned short* pb3 = Wg + (size_t)(n0 + 48 + lr) * DIN + q * 8;
#pragma unroll
        for (int k = 0; k < DIN; k += 32) {
            bf16x8 a0 = *(const bf16x8*)(la0 + k);
            bf16x8 a1 = *(const bf16x8*)(la1 + k);
            bf16x8 b0 = *(const bf16x8*)(pb0 + k);
            bf16x8 b1 = *(const bf16x8*)(pb1 + k);
            bf16x8 b2 = *(const bf16x8*)(pb2 + k);
            bf16x8 b3 = *(const bf16x8*)(pb3 + k);
            accm[0][0] = __builtin_amdgcn_mfma_f32_16x16x32_bf16(a0, b0, accm[0][0], 0, 0, 0);
            accm[0][1] = __builtin_amdgcn_mfma_f32_16x16x32_bf16(a0, b1, accm[0][1], 0, 0, 0);
            accm[0][2] = __builtin_amdgcn_mfma_f32_16x16x32_bf16(a0, b2, accm[0][2], 0, 0, 0);
            accm[0][3] = __builtin_amdgcn_mfma_f32_16x16x32_bf16(a0, b3, accm[0][3], 0, 0, 0);
            accm[1][0] = __builtin_amdgcn_mfma_f32_16x16x32_bf16(a1, b0, accm[1][0], 0, 0, 0);
            accm[1][1] = __builtin_amdgcn_mfma_f32_16x16x32_bf16(a1, b1, accm[1][1], 0, 0, 0);
            accm[1][2] = __builtin_amdgcn_mfma_f32_16x16x32_bf16(a1, b2, accm[1][2], 0, 0, 0);
            accm[1][3] = __builtin_amdgcn_mfma_f32_16x16x32_bf16(a1, b3, accm[1][3], 0, 0, 0);
        }
    }
    {   // seg 2: self features from global
        int ra0 = m0 + lr;       if (ra0 >= N) ra0 = N - 1;
        int ra1 = m0 + 16 + lr;  if (ra1 >= N) ra1 = N - 1;
        const unsigned short* pa0 = xself + (size_t)ra0 * DIN + q * 8;
        const unsigned short* pa1 = xself + (size_t)ra1 * DIN + q * 8;
        const unsigned short* pb0 = W2 + (size_t)(n0 + lr) * DIN + q * 8;
        const unsigned short* pb1 = W2 + (size_t)(n0 + 16 + lr) * DIN + q * 8;
        const unsigned short* pb2 = W2 + (size_t)(n0 + 32 + lr) * DIN + q * 8;
        const unsigned short* pb3 = W2 + (size_t)(n0 + 48 + lr) * DIN + q * 8;
#pragma unroll
        for (int k = 0; k < DIN; k += 32) {
            bf16x8 a0 = *(const bf16x8*)(pa0 + k);
            bf16x8 a1 = *(const bf16x8*)(pa1 + k);
            bf16x8 b0 = *(const bf16x8*)(pb0 + k);
            bf16x8 b1 = *(const bf16x8*)(pb1 + k);
            bf16x8 b2 = *(const bf16x8*)(pb2 + k);
            bf16x8 b3 = *(const bf16x8*)(pb3 + k);
            accm[0][0] = __builtin_amdgcn_mfma_f32_16x16x32_bf16(a0, b0, accm[0][0], 0, 0, 0);
            accm[0][1] = __builtin_amdgcn_mfma_f32_16x16x32_bf16(a0, b1, accm[0][1], 0, 0, 0);
            accm[0][2] = __builtin_amdgcn_mfma_f32_16x16x32_bf16(a0, b2, accm[0][2], 0, 0, 0);
            accm[0][3] = __builtin_amdgcn_mfma_f32_16x16x32_bf16(a0, b3, accm[0][3], 0, 0, 0);
            accm[1][0] = __builtin_amdgcn_mfma_f32_16x16x32_bf16(a1, b0, accm[1][0], 0, 0, 0);
            accm[1][1] = __builtin_amdgcn_mfma_f32_16x16x32_bf16(a1, b1, accm[1][1], 0, 0, 0);
            accm[1][2] = __builtin_amdgcn_mfma_f32_16x16x32_bf16(a1, b2, accm[1][2], 0, 0, 0);
            accm[1][3] = __builtin_amdgcn_mfma_f32_16x16x32_bf16(a1, b3, accm[1][3], 0, 0, 0);
        }
    }

    // epilogue: bias + relu -> bf16 h
#pragma unroll
    for (int mt = 0; mt < 2; ++mt) {
#pragma unroll
        for (int nt = 0; nt < 4; ++nt) {
            int colc = n0 + nt * 16 + lr;
            float b = bias[colc];
#pragma unroll
            for (int rr = 0; rr < 4; ++rr) {
                int row = m0 + mt * 16 + q * 4 + rr;
                if (row < N)
                    h[(size_t)row * DH + colc] = f2bf(fmaxf(accm[mt][nt][rr] + b, 0.f));
            }
        }
    }
}

// ---------------- layer-1 transform (y=2): z_A, z_B + self -> out ----------------
__global__ __launch_bounds__(256) void l1_transform_kernel(
    const unsigned short* __restrict__ h_tx, const unsigned short* __restrict__ h_ad,
    const float* __restrict__ Wl1_tt, const float* __restrict__ Wl1_ta,
    const float* __restrict__ Wl1_aa, const float* __restrict__ Wl1_at,
    const float* __restrict__ Wr1c, const float* __restrict__ b1c,
    float* __restrict__ z, float* __restrict__ outp, int n)
{
    const int type = blockIdx.y;
    const unsigned short* h = type ? h_ad : h_tx;
    const float* WzA   = type ? Wl1_aa : Wl1_tt;
    const float* WzB   = type ? Wl1_at : Wl1_ta;
    const float* Wself = Wr1c + type * 2 * DH;
    const float* bself = b1c + type * 2;
    float* zA = type ? (z + (size_t)1 * n * 2) : z;                      // z_aa / z_tt
    float* zB = type ? (z + (size_t)2 * n * 2) : (z + (size_t)3 * n * 2); // z_at / z_ta
    float* outSelf = outp + (size_t)type * n * 2;

    int wave = threadIdx.x >> 6;
    int lane = threadIdx.x & 63;
    int node = blockIdx.x * 4 + wave;
    if (node >= n) return;
    uint2 hu = *(const uint2*)(h + (size_t)node * DH + lane * 4);
    float4 hv;
    hv.x = bf2f(hu.x & 0xffffu); hv.y = bf2f(hu.x >> 16);
    hv.z = bf2f(hu.y & 0xffffu); hv.w = bf2f(hu.y >> 16);
    const float4 wa0 = *(const float4*)(WzA + lane * 4);
    const float4 wa1 = *(const float4*)(WzA + DH + lane * 4);
    const float4 wb0 = *(const float4*)(WzB + lane * 4);
    const float4 wb1 = *(const float4*)(WzB + DH + lane * 4);
    const float4 ws0 = *(const float4*)(Wself + lane * 4);
    const float4 ws1 = *(const float4*)(Wself + DH + lane * 4);
    float v[6];
    v[0] = hv.x * wa0.x + hv.y * wa0.y + hv.z * wa0.z + hv.w * wa0.w;
    v[1] = hv.x * wa1.x + hv.y * wa1.y + hv.z * wa1.z + hv.w * wa1.w;
    v[2] = hv.x * wb0.x + hv.y * wb0.y + hv.z * wb0.z + hv.w * wb0.w;
    v[3] = hv.x * wb1.x + hv.y * wb1.y + hv.z * wb1.z + hv.w * wb1.w;
    v[4] = hv.x * ws0.x + hv.y * ws0.y + hv.z * ws0.z + hv.w * ws0.w;
    v[5] = hv.x * ws1.x + hv.y * ws1.y + hv.z * ws1.z + hv.w * ws1.w;
#pragma unroll
    for (int m = 32; m > 0; m >>= 1) {
#pragma unroll
        for (int qq = 0; qq < 6; ++qq) v[qq] += __shfl_xor(v[qq], m, 64);
    }
    if (lane == 0) {
        zA[node * 2]     = v[0];
        zA[node * 2 + 1] = v[1];
        zB[node * 2]     = v[2];
        zB[node * 2 + 1] = v[3];
        outSelf[node * 2]     = v[4] + bself[0];
        outSelf[node * 2 + 1] = v[5] + bself[1];
    }
}

// ---------------- layer-1 aggregate (y=2): out += mean_A(zA) + mean_B(zB) --------
__global__ __launch_bounds__(256) void l1_agg_kernel(
    const int* __restrict__ rowptr, const int* __restrict__ cnt, const int* __restrict__ col,
    const float* __restrict__ z, float* __restrict__ out, int N)
{
    const int type = blockIdx.y;
    const int rA = type ? 1 : 0;
    const int rB = type ? 3 : 2;
    const float* zA = type ? (z + (size_t)1 * N * 2) : z;
    const float* zB = type ? (z + (size_t)3 * N * 2) : (z + (size_t)2 * N * 2);
    float* outp = out + (size_t)type * N * 2;

    int i = blockIdx.x * blockDim.x + threadIdx.x;
    if (i >= N) return;
    float ax = 0.f, ay = 0.f;
    {
        int b = rowptr[rA * N + i], c = cnt[rA * N + i];
        const int* cl = col + b;
        float sx = 0.f, sy = 0.f;
        for (int e = 0; e < c; ++e) {
            int s = cl[e];
            sx += zA[s * 2]; sy += zA[s * 2 + 1];
        }
        float sc = 1.0f / fmaxf((float)c, 1.0f);
        ax += sx * sc; ay += sy * sc;
    }
    {
        int b = rowptr[rB * N + i], c = cnt[rB * N + i];
        const int* cl = col + b;
        float sx = 0.f, sy = 0.f;
        for (int e = 0; e < c; ++e) {
            int s = cl[e];
            sx += zB[s * 2]; sy += zB[s * 2 + 1];
        }
        float sc = 1.0f / fmaxf((float)c, 1.0f);
        ax += sx * sc; ay += sy * sc;
    }
    outp[i * 2]     += ax;
    outp[i * 2 + 1] += ay;
}

// ---------------- launch ----------------
extern "C" void kernel_launch(void* const* d_in, const int* in_sizes, int n_in,
                              void* d_out, int out_size, void* d_ws, size_t ws_size,
                              hipStream_t stream)
{
    const float* x_tx   = (const float*)d_in[0];
    const float* x_addr = (const float*)d_in[1];
    const int* e_tt = (const int*)d_in[2];
    const int* e_aa = (const int*)d_in[3];
    const int* e_at = (const int*)d_in[4];
    const int* e_ta = (const int*)d_in[5];
    const float* Wl0_tt = (const float*)d_in[6];
    const float* bl0_tt = (const float*)d_in[7];
    const float* Wr0_tt = (const float*)d_in[8];
    const float* Wl0_aa = (const float*)d_in[9];
    const float* bl0_aa = (const float*)d_in[10];
    const float* Wr0_aa = (const float*)d_in[11];
    const float* Wl0_at = (const float*)d_in[12];
    const float* bl0_at = (const float*)d_in[13];
    const float* Wr0_at = (const float*)d_in[14];
    const float* Wl0_ta = (const float*)d_in[15];
    const float* bl0_ta = (const float*)d_in[16];
    const float* Wr0_ta = (const float*)d_in[17];
    const float* Wl1_tt = (const float*)d_in[18];
    const float* bl1_tt = (const float*)d_in[19];
    const float* Wr1_tt = (const float*)d_in[20];
    const float* Wl1_aa = (const float*)d_in[21];
    const float* bl1_aa = (const float*)d_in[22];
    const float* Wr1_aa = (const float*)d_in[23];
    const float* Wl1_at = (const float*)d_in[24];
    const float* bl1_at = (const float*)d_in[25];
    const float* Wr1_at = (const float*)d_in[26];
    const float* Wl1_ta = (const float*)d_in[27];
    const float* bl1_ta = (const float*)d_in[28];
    const float* Wr1_ta = (const float*)d_in[29];

    const int N = in_sizes[0] / DIN;   // 50000
    const int E = in_sizes[2] / 2;     // 400000

    size_t off = 0;
    char* base = (char*)d_ws;
    auto alloc = [&](size_t bytes) -> void* {
        void* p = base + off;
        off += (bytes + 255) & ~(size_t)255;
        return p;
    };
    int*   cnt    = (int*)  alloc((size_t)4 * N * 4);   // 800000 B (256-mult) ->
    int*   cursor = (int*)  alloc((size_t)4 * N * 4);   //   contiguous with cnt
    int*   rowptr = (int*)  alloc((size_t)4 * N * 4);
    int*   col    = (int*)  alloc((size_t)4 * E * 4);
    unsigned long long* desc = (unsigned long long*)alloc(257 * 8);
    unsigned short* xb_tx = (unsigned short*)alloc((size_t)N * DIN * 2);
    unsigned short* xb_ad = (unsigned short*)alloc((size_t)N * DIN * 2);
    unsigned short* h_tx  = (unsigned short*)alloc((size_t)N * DH * 2);
    unsigned short* h_ad  = (unsigned short*)alloc((size_t)N * DH * 2);
    float* z      = (float*)alloc((size_t)4 * N * 2 * 4);
    unsigned short* wb_tt  = (unsigned short*)alloc((size_t)DH * DIN * 2);
    unsigned short* wb_aa  = (unsigned short*)alloc((size_t)DH * DIN * 2);
    unsigned short* wb_at  = (unsigned short*)alloc((size_t)DH * DIN * 2);
    unsigned short* wb_ta  = (unsigned short*)alloc((size_t)DH * DIN * 2);
    unsigned short* wr0c_tx = (unsigned short*)alloc((size_t)DH * DIN * 2);
    unsigned short* wr0c_ad = (unsigned short*)alloc((size_t)DH * DIN * 2);
    float* b0c    = (float*)alloc((size_t)2 * DH * 4);
    float* Wr1c   = (float*)alloc((size_t)2 * 2 * DH * 4);
    float* b1c    = (float*)alloc((size_t)2 * 2 * 4);
    (void)ws_size;

    float* outp = (float*)d_out;
    const int n4 = 4 * N;

    // 1. setup (zero cnt/cursor/desc + converts + weight prep)
    {
        int nconv = N * DIN / 8;
        setup_kernel<<<(nconv + 255) / 256, 256, 0, stream>>>(
            x_tx, x_addr,
            Wl0_tt, Wl0_aa, Wl0_at, Wl0_ta,
            Wr0_tt, Wr0_aa, Wr0_at, Wr0_ta,
            bl0_tt, bl0_aa, bl0_at, bl0_ta,
            Wr1_tt, Wr1_aa, Wr1_at, Wr1_ta,
            bl1_tt, bl1_aa, bl1_at, bl1_ta,
            xb_tx, xb_ad, cnt, desc,
            wb_tt, wb_aa, wb_at, wb_ta, wr0c_tx, wr0c_ad, b0c, Wr1c, b1c, N);
    }
    // 2. counts
    {
        dim3 g((E + 255) / 256, 4);
        count_kernel<<<g, 256, 0, stream>>>(e_tt, e_aa, e_at, e_ta, cnt, E, N);
    }
    // 3. scan (single-kernel lookback)
    {
        int nb = (n4 + 1023) / 1024;
        scan_kernel<<<nb, 1024, 0, stream>>>(cnt, rowptr, desc, n4);
    }
    // 4. fill
    {
        dim3 g((E + 255) / 256, 4);
        fill_kernel<<<g, 256, 0, stream>>>(e_tt, e_aa, e_at, e_ta, rowptr, cursor, col, E, N);
    }
    // 5. fused layer-0 (both types)
    {
        dim3 g((N + 31) / 32, 2);
        fused0_kernel<<<g, 256, 0, stream>>>(
            xb_tx, xb_ad, rowptr, cnt, col,
            wb_tt, wb_at, wr0c_tx, wb_aa, wb_ta, wr0c_ad,
            b0c, h_tx, h_ad, N);
    }
    // 6. layer-1 transforms (both types)
    {
        dim3 g((N + 3) / 4, 2);
        l1_transform_kernel<<<g, 256, 0, stream>>>(
            h_tx, h_ad, Wl1_tt, Wl1_ta, Wl1_aa, Wl1_at, Wr1c, b1c, z, outp, N);
    }
    // 7. layer-1 aggregation (both types)
    {
        dim3 g((N + 255) / 256, 2);
        l1_agg_kernel<<<g, 256, 0, stream>>>(rowptr, cnt, col, z, outp, N);
    }
}

// Round 4
// 449.074 us; speedup vs baseline: 2.0459x; 1.2603x over previous
//
#include <hip/hip_runtime.h>

// HeteroSAGE on MI355X — round 4: gather un-fused (occupancy back), layer-1
// transform fused into gemm0 epilogue (h never stored), rank-based CSR fill.
//
// Pipeline (7 dispatches):
//   1. setup: zero cnt/desc, convert x->bf16, fold weights, build Wz (6x256 /type)
//   2. count (y=4): in-degree atomics; stores per-edge rank
//   3. scan: single-kernel decoupled-lookback exclusive prefix
//   4. fill (y=4): col[rowptr[d]+rank[e]] = src  (no atomics)
//   5. agg (y=4): per-(node,rel) mean, quarter-wave, 8-edge unroll -> aggb bf16
//   6. gemm0z (y=2): MFMA 3 segs (relA, relB, self) -> h in regs -> relu+bias
//      -> z[6] dots vs Wz (LDS) -> z arrays + self term -> out
//   7. l1_agg (y=2): out += mean_r(z) via CSR walk

#define DIN 128
#define DH  256

typedef __attribute__((ext_vector_type(8))) short bf16x8;
typedef __attribute__((ext_vector_type(4))) float f32x4;

__device__ __forceinline__ float bf2f(unsigned int u) {
    return __uint_as_float(u << 16);
}
__device__ __forceinline__ unsigned short f2bf(float f) {
    unsigned int u = __float_as_uint(f);
    u = (u + 0x7fffu + ((u >> 16) & 1u)) >> 16;   // RNE
    return (unsigned short)u;
}
__device__ __forceinline__ void acc_u4(float* a, uint4 u) {
    a[0] += bf2f(u.x & 0xffffu); a[1] += bf2f(u.x >> 16);
    a[2] += bf2f(u.y & 0xffffu); a[3] += bf2f(u.y >> 16);
    a[4] += bf2f(u.z & 0xffffu); a[5] += bf2f(u.z >> 16);
    a[6] += bf2f(u.w & 0xffffu); a[7] += bf2f(u.w >> 16);
}

// ---------------- setup ----------------
__global__ __launch_bounds__(256) void setup_kernel(
    const float* __restrict__ x_tx, const float* __restrict__ x_addr,
    const float* __restrict__ Wl0_tt, const float* __restrict__ Wl0_aa,
    const float* __restrict__ Wl0_at, const float* __restrict__ Wl0_ta,
    const float* __restrict__ Wr0_tt, const float* __restrict__ Wr0_aa,
    const float* __restrict__ Wr0_at, const float* __restrict__ Wr0_ta,
    const float* __restrict__ bl0_tt, const float* __restrict__ bl0_aa,
    const float* __restrict__ bl0_at, const float* __restrict__ bl0_ta,
    const float* __restrict__ Wl1_tt, const float* __restrict__ Wl1_aa,
    const float* __restrict__ Wl1_at, const float* __restrict__ Wl1_ta,
    const float* __restrict__ Wr1_tt, const float* __restrict__ Wr1_aa,
    const float* __restrict__ Wr1_at, const float* __restrict__ Wr1_ta,
    const float* __restrict__ bl1_tt, const float* __restrict__ bl1_aa,
    const float* __restrict__ bl1_at, const float* __restrict__ bl1_ta,
    unsigned short* __restrict__ xb_tx, unsigned short* __restrict__ xb_ad,
    int* __restrict__ cnt, unsigned long long* __restrict__ desc,
    unsigned short* __restrict__ wb_tt, unsigned short* __restrict__ wb_aa,
    unsigned short* __restrict__ wb_at, unsigned short* __restrict__ wb_ta,
    unsigned short* __restrict__ wr0c_tx, unsigned short* __restrict__ wr0c_ad,
    float* __restrict__ b0c, float* __restrict__ wzall, float* __restrict__ b1c,
    int N)
{
    int i = blockIdx.x * blockDim.x + threadIdx.x;
    int nconv = N * DIN / 8;                 // 800000
    if (i < nconv) {
        {
            const float4* p = (const float4*)(x_tx + (size_t)i * 8);
            float4 a = p[0], b = p[1];
            uint4 o;
            o.x = (unsigned)f2bf(a.x) | ((unsigned)f2bf(a.y) << 16);
            o.y = (unsigned)f2bf(a.z) | ((unsigned)f2bf(a.w) << 16);
            o.z = (unsigned)f2bf(b.x) | ((unsigned)f2bf(b.y) << 16);
            o.w = (unsigned)f2bf(b.z) | ((unsigned)f2bf(b.w) << 16);
            *(uint4*)(xb_tx + (size_t)i * 8) = o;
        }
        {
            const float4* p = (const float4*)(x_addr + (size_t)i * 8);
            float4 a = p[0], b = p[1];
            uint4 o;
            o.x = (unsigned)f2bf(a.x) | ((unsigned)f2bf(a.y) << 16);
            o.y = (unsigned)f2bf(a.z) | ((unsigned)f2bf(a.w) << 16);
            o.z = (unsigned)f2bf(b.x) | ((unsigned)f2bf(b.y) << 16);
            o.w = (unsigned)f2bf(b.z) | ((unsigned)f2bf(b.w) << 16);
            *(uint4*)(xb_ad + (size_t)i * 8) = o;
        }
    }
    if (i < N)                                // 4N ints = N int4
        ((int4*)cnt)[i] = make_int4(0, 0, 0, 0);
    if (i < 257) desc[i] = 0ULL;
    if (i < DH * DIN) {
        wb_tt[i] = f2bf(Wl0_tt[i]);
        wb_aa[i] = f2bf(Wl0_aa[i]);
        wb_at[i] = f2bf(Wl0_at[i]);
        wb_ta[i] = f2bf(Wl0_ta[i]);
        wr0c_tx[i] = f2bf(Wr0_tt[i] + Wr0_at[i]);
        wr0c_ad[i] = f2bf(Wr0_aa[i] + Wr0_ta[i]);
    }
    if (i < DH) {
        b0c[i]      = bl0_tt[i] + bl0_at[i];
        b0c[DH + i] = bl0_aa[i] + bl0_ta[i];
    }
    if (i < 2 * DH) {                         // wz: [type][6][256] fp32
        int type = i >> 8;
        int c = i & 255;
        const float* A = type ? Wl1_aa : Wl1_tt;
        const float* B = type ? Wl1_at : Wl1_ta;
        float s0 = type ? (Wr1_aa[c] + Wr1_ta[c]) : (Wr1_tt[c] + Wr1_at[c]);
        float s1 = type ? (Wr1_aa[DH + c] + Wr1_ta[DH + c])
                        : (Wr1_tt[DH + c] + Wr1_at[DH + c]);
        float* wz = wzall + (size_t)type * 6 * DH;
        wz[0 * DH + c] = A[c];
        wz[1 * DH + c] = A[DH + c];
        wz[2 * DH + c] = B[c];
        wz[3 * DH + c] = B[DH + c];
        wz[4 * DH + c] = s0;
        wz[5 * DH + c] = s1;
    }
    if (i < 2) {
        b1c[i]     = bl1_tt[i] + bl1_at[i];
        b1c[2 + i] = bl1_aa[i] + bl1_ta[i];
    }
}

// ---------------- CSR build ----------------
__global__ __launch_bounds__(256) void count_kernel(
    const int* __restrict__ e0, const int* __restrict__ e1,
    const int* __restrict__ e2, const int* __restrict__ e3,
    int* __restrict__ cnt, int* __restrict__ rank, int E, int N)
{
    int r = blockIdx.y;
    const int* e = (r == 0) ? e0 : (r == 1) ? e1 : (r == 2) ? e2 : e3;
    int i = blockIdx.x * blockDim.x + threadIdx.x;
    if (i < E) {
        int d = e[E + i];
        rank[(size_t)r * E + i] = atomicAdd(&cnt[r * N + d], 1);
    }
}

// single-kernel decoupled-lookback exclusive scan (ticket-ordered)
__global__ __launch_bounds__(1024) void scan_kernel(
    const int* __restrict__ cnt, int* __restrict__ excl,
    unsigned long long* __restrict__ desc, int n)
{
    __shared__ int sdata[1024];
    __shared__ int sseg;
    __shared__ int sprev;
    if (threadIdx.x == 0) sseg = (int)atomicAdd(&desc[256], 1ULL);
    __syncthreads();
    int seg = sseg;
    int i = seg * 1024 + threadIdx.x;
    int v = (i < n) ? cnt[i] : 0;
    sdata[threadIdx.x] = v;
    __syncthreads();
    for (int off = 1; off < 1024; off <<= 1) {
        int t = (threadIdx.x >= off) ? sdata[threadIdx.x - off] : 0;
        __syncthreads();
        sdata[threadIdx.x] += t;
        __syncthreads();
    }
    if (threadIdx.x == 0) {
        int total = sdata[1023];
        int prev = 0;
        if (seg == 0) {
            atomicExch(&desc[0], ((unsigned long long)(unsigned)total << 2) | 2ULL);
        } else {
            atomicExch(&desc[seg], ((unsigned long long)(unsigned)total << 2) | 1ULL);
            int j = seg - 1;
            for (;;) {
                unsigned long long d = atomicAdd(&desc[j], 0ULL);
                unsigned st = (unsigned)(d & 3ULL);
                if (st == 0u) continue;
                prev += (int)(d >> 2);
                if (st == 2u) break;
                --j;
            }
            atomicExch(&desc[seg],
                       ((unsigned long long)(unsigned)(prev + total) << 2) | 2ULL);
        }
        sprev = prev;
    }
    __syncthreads();
    if (i < n) excl[i] = sprev + sdata[threadIdx.x] - v;
}

__global__ __launch_bounds__(256) void fill_kernel(
    const int* __restrict__ e0, const int* __restrict__ e1,
    const int* __restrict__ e2, const int* __restrict__ e3,
    const int* __restrict__ rowptr, const int* __restrict__ rank,
    int* __restrict__ col, int E, int N)
{
    int r = blockIdx.y;
    const int* e = (r == 0) ? e0 : (r == 1) ? e1 : (r == 2) ? e2 : e3;
    int i = blockIdx.x * blockDim.x + threadIdx.x;
    if (i < E) {
        int s = e[i];
        int d = e[E + i];
        col[rowptr[r * N + d] + rank[(size_t)r * E + i]] = s;
    }
}

// ---------------- layer-0 mean aggregation: quarter-wave, 8-edge unroll --------
__global__ __launch_bounds__(256) void agg_kernel(
    const unsigned short* __restrict__ xb_tx, const unsigned short* __restrict__ xb_ad,
    const int* __restrict__ rowptr, const int* __restrict__ cnt,
    const int* __restrict__ col, unsigned short* __restrict__ aggb, int N)
{
    int r = blockIdx.y;                        // 0=tt 1=aa 2=at 3=ta
    const unsigned short* xs = (r == 0 || r == 3) ? xb_tx : xb_ad;
    int wave = threadIdx.x >> 6;
    int l    = threadIdx.x & 63;
    int node = blockIdx.x * 4 + wave;
    if (node >= N) return;
    int base = rowptr[r * N + node];
    int c    = cnt[r * N + node];
    const int* cl = col + base;
    int q = l >> 4;
    int d = l & 15;
    float acc[8] = {};
    float acc2[8] = {};
    int e0 = 0;
    for (; e0 + 8 <= c; e0 += 8) {
        int sA = cl[e0 + q];
        int sB = cl[e0 + 4 + q];
        uint4 uA = *(const uint4*)(xs + (size_t)sA * DIN + d * 8);
        uint4 uB = *(const uint4*)(xs + (size_t)sB * DIN + d * 8);
        acc_u4(acc, uA);
        acc_u4(acc2, uB);
    }
    for (; e0 < c; e0 += 4) {
        int e = e0 + q;
        if (e < c) {
            int s = cl[e];
            uint4 u = *(const uint4*)(xs + (size_t)s * DIN + d * 8);
            acc_u4(acc, u);
        }
    }
#pragma unroll
    for (int j = 0; j < 8; ++j) {
        acc[j] += acc2[j];
        acc[j] += __shfl_xor(acc[j], 16, 64);
        acc[j] += __shfl_xor(acc[j], 32, 64);
    }
    if (q == 0) {
        float sc = 1.0f / fmaxf((float)c, 1.0f);
        uint4 o;
        o.x = (unsigned)f2bf(acc[0] * sc) | ((unsigned)f2bf(acc[1] * sc) << 16);
        o.y = (unsigned)f2bf(acc[2] * sc) | ((unsigned)f2bf(acc[3] * sc) << 16);
        o.z = (unsigned)f2bf(acc[4] * sc) | ((unsigned)f2bf(acc[5] * sc) << 16);
        o.w = (unsigned)f2bf(acc[6] * sc) | ((unsigned)f2bf(acc[7] * sc) << 16);
        *(uint4*)(aggb + ((size_t)r * N + node) * DIN + d * 8) = o;
    }
}

// ---------------- gemm0 + fused layer-1 transform ----------------
// y = dst type. 32 rows/block, 4 waves each owning 64 of 256 cols.
// h = relu(meanA@W0^T + meanB@W1^T + x_self@W2^T + b) kept in registers;
// epilogue computes z[6] = h . Wz[zi] per row (shfl + LDS-atomic reduce).
__global__ __launch_bounds__(256) void gemm0z_kernel(
    const unsigned short* __restrict__ xb_tx, const unsigned short* __restrict__ xb_ad,
    const unsigned short* __restrict__ aggb,
    const unsigned short* __restrict__ wb_tt, const unsigned short* __restrict__ wb_at,
    const unsigned short* __restrict__ wr0c_tx,
    const unsigned short* __restrict__ wb_aa, const unsigned short* __restrict__ wb_ta,
    const unsigned short* __restrict__ wr0c_ad,
    const float* __restrict__ b0c, const float* __restrict__ wzall,
    const float* __restrict__ b1c,
    float* __restrict__ z, float* __restrict__ outp, int N)
{
    __shared__ float wzs[6 * DH];
    __shared__ float zacc[32 * 6];
    const int type = blockIdx.y;
    const unsigned short* xself = type ? xb_ad : xb_tx;
    const unsigned short* A0 = aggb + (size_t)(type ? 1 : 0) * N * DIN;  // aa / tt
    const unsigned short* A1 = aggb + (size_t)(type ? 3 : 2) * N * DIN;  // ta / at
    const unsigned short* W0 = type ? wb_aa   : wb_tt;
    const unsigned short* W1 = type ? wb_ta   : wb_at;
    const unsigned short* W2 = type ? wr0c_ad : wr0c_tx;
    const float* bias = b0c + type * DH;
    float* zA = type ? (z + (size_t)1 * N * 2) : z;                       // aa / tt
    float* zB = type ? (z + (size_t)2 * N * 2) : (z + (size_t)3 * N * 2); // at / ta
    float* outSelf = outp + (size_t)type * N * 2;

    const int t  = threadIdx.x;
    const int wv = t >> 6;
    const int l  = t & 63;
    const int q  = l >> 4;
    const int lr = l & 15;
    const int m0 = blockIdx.x * 32;
    const int n0 = wv * 64;

    // stage Wz + zero zacc (used only after the barrier below)
    {
        const float* wzg = wzall + (size_t)type * 6 * DH;
        for (int i = t; i < 6 * DH; i += 256) wzs[i] = wzg[i];
        if (t < 192) zacc[t] = 0.f;
    }

    f32x4 accm[2][4] = {};
    int ra0 = m0 + lr;       if (ra0 >= N) ra0 = N - 1;
    int ra1 = m0 + 16 + lr;  if (ra1 >= N) ra1 = N - 1;
    const unsigned short* As[3] = {A0, A1, xself};
    const unsigned short* Ws[3] = {W0, W1, W2};
#pragma unroll
    for (int seg = 0; seg < 3; ++seg) {
        const unsigned short* A = As[seg];
        const unsigned short* W = Ws[seg];
        const unsigned short* pa0 = A + (size_t)ra0 * DIN + q * 8;
        const unsigned short* pa1 = A + (size_t)ra1 * DIN + q * 8;
        const unsigned short* pb0 = W + (size_t)(n0 + lr) * DIN + q * 8;
        const unsigned short* pb1 = W + (size_t)(n0 + 16 + lr) * DIN + q * 8;
        const unsigned short* pb2 = W + (size_t)(n0 + 32 + lr) * DIN + q * 8;
        const unsigned short* pb3 = W + (size_t)(n0 + 48 + lr) * DIN + q * 8;
#pragma unroll
        for (int k = 0; k < DIN; k += 32) {
            bf16x8 a0 = *(const bf16x8*)(pa0 + k);
            bf16x8 a1 = *(const bf16x8*)(pa1 + k);
            bf16x8 b0 = *(const bf16x8*)(pb0 + k);
            bf16x8 b1 = *(const bf16x8*)(pb1 + k);
            bf16x8 b2 = *(const bf16x8*)(pb2 + k);
            bf16x8 b3 = *(const bf16x8*)(pb3 + k);
            accm[0][0] = __builtin_amdgcn_mfma_f32_16x16x32_bf16(a0, b0, accm[0][0], 0, 0, 0);
            accm[0][1] = __builtin_amdgcn_mfma_f32_16x16x32_bf16(a0, b1, accm[0][1], 0, 0, 0);
            accm[0][2] = __builtin_amdgcn_mfma_f32_16x16x32_bf16(a0, b2, accm[0][2], 0, 0, 0);
            accm[0][3] = __builtin_amdgcn_mfma_f32_16x16x32_bf16(a0, b3, accm[0][3], 0, 0, 0);
            accm[1][0] = __builtin_amdgcn_mfma_f32_16x16x32_bf16(a1, b0, accm[1][0], 0, 0, 0);
            accm[1][1] = __builtin_amdgcn_mfma_f32_16x16x32_bf16(a1, b1, accm[1][1], 0, 0, 0);
            accm[1][2] = __builtin_amdgcn_mfma_f32_16x16x32_bf16(a1, b2, accm[1][2], 0, 0, 0);
            accm[1][3] = __builtin_amdgcn_mfma_f32_16x16x32_bf16(a1, b3, accm[1][3], 0, 0, 0);
        }
    }
    __syncthreads();   // zacc zeroed + wzs staged before epilogue atomics

    // per-lane weights for the 4 owned col-groups
    float bias_nt[4];
    float wzr[6][4];
#pragma unroll
    for (int nt = 0; nt < 4; ++nt) {
        int colc = n0 + nt * 16 + lr;
        bias_nt[nt] = bias[colc];
#pragma unroll
        for (int zi = 0; zi < 6; ++zi) wzr[zi][nt] = wzs[zi * DH + colc];
    }

#pragma unroll
    for (int mt = 0; mt < 2; ++mt) {
#pragma unroll
        for (int rr = 0; rr < 4; ++rr) {
            float hv[4];
#pragma unroll
            for (int nt = 0; nt < 4; ++nt)
                hv[nt] = fmaxf(accm[mt][nt][rr] + bias_nt[nt], 0.f);
            float s[6];
#pragma unroll
            for (int zi = 0; zi < 6; ++zi) {
                s[zi] = hv[0] * wzr[zi][0] + hv[1] * wzr[zi][1]
                      + hv[2] * wzr[zi][2] + hv[3] * wzr[zi][3];
#pragma unroll
                for (int m = 1; m < 16; m <<= 1)
                    s[zi] += __shfl_xor(s[zi], m, 64);
            }
            if (lr == 0) {
                int row = mt * 16 + q * 4 + rr;
#pragma unroll
                for (int zi = 0; zi < 6; ++zi)
                    atomicAdd(&zacc[row * 6 + zi], s[zi]);
            }
        }
    }
    __syncthreads();

    if (t < 192) {
        int row = t / 6, zi = t % 6;
        int node = m0 + row;
        if (node < N) {
            float v = zacc[t];
            if (zi < 2)      zA[node * 2 + zi] = v;
            else if (zi < 4) zB[node * 2 + zi - 2] = v;
            else             outSelf[node * 2 + zi - 4] = v + b1c[type * 2 + zi - 4];
        }
    }
}

// ---------------- layer-1 aggregate (y=2): out += mean_A(zA) + mean_B(zB) --------
__global__ __launch_bounds__(256) void l1_agg_kernel(
    const int* __restrict__ rowptr, const int* __restrict__ cnt, const int* __restrict__ col,
    const float* __restrict__ z, float* __restrict__ out, int N)
{
    const int type = blockIdx.y;
    const int rA = type ? 1 : 0;
    const int rB = type ? 3 : 2;
    const float* zA = type ? (z + (size_t)1 * N * 2) : z;
    const float* zB = type ? (z + (size_t)3 * N * 2) : (z + (size_t)2 * N * 2);
    float* outp = out + (size_t)type * N * 2;

    int i = blockIdx.x * blockDim.x + threadIdx.x;
    if (i >= N) return;
    float ax = 0.f, ay = 0.f;
    {
        int b = rowptr[rA * N + i], c = cnt[rA * N + i];
        const int* cl = col + b;
        float sx = 0.f, sy = 0.f;
        for (int e = 0; e < c; ++e) {
            int s = cl[e];
            sx += zA[s * 2]; sy += zA[s * 2 + 1];
        }
        float sc = 1.0f / fmaxf((float)c, 1.0f);
        ax += sx * sc; ay += sy * sc;
    }
    {
        int b = rowptr[rB * N + i], c = cnt[rB * N + i];
        const int* cl = col + b;
        float sx = 0.f, sy = 0.f;
        for (int e = 0; e < c; ++e) {
            int s = cl[e];
            sx += zB[s * 2]; sy += zB[s * 2 + 1];
        }
        float sc = 1.0f / fmaxf((float)c, 1.0f);
        ax += sx * sc; ay += sy * sc;
    }
    outp[i * 2]     += ax;
    outp[i * 2 + 1] += ay;
}

// ---------------- launch ----------------
extern "C" void kernel_launch(void* const* d_in, const int* in_sizes, int n_in,
                              void* d_out, int out_size, void* d_ws, size_t ws_size,
                              hipStream_t stream)
{
    const float* x_tx   = (const float*)d_in[0];
    const float* x_addr = (const float*)d_in[1];
    const int* e_tt = (const int*)d_in[2];
    const int* e_aa = (const int*)d_in[3];
    const int* e_at = (const int*)d_in[4];
    const int* e_ta = (const int*)d_in[5];
    const float* Wl0_tt = (const float*)d_in[6];
    const float* bl0_tt = (const float*)d_in[7];
    const float* Wr0_tt = (const float*)d_in[8];
    const float* Wl0_aa = (const float*)d_in[9];
    const float* bl0_aa = (const float*)d_in[10];
    const float* Wr0_aa = (const float*)d_in[11];
    const float* Wl0_at = (const float*)d_in[12];
    const float* bl0_at = (const float*)d_in[13];
    const float* Wr0_at = (const float*)d_in[14];
    const float* Wl0_ta = (const float*)d_in[15];
    const float* bl0_ta = (const float*)d_in[16];
    const float* Wr0_ta = (const float*)d_in[17];
    const float* Wl1_tt = (const float*)d_in[18];
    const float* bl1_tt = (const float*)d_in[19];
    const float* Wr1_tt = (const float*)d_in[20];
    const float* Wl1_aa = (const float*)d_in[21];
    const float* bl1_aa = (const float*)d_in[22];
    const float* Wr1_aa = (const float*)d_in[23];
    const float* Wl1_at = (const float*)d_in[24];
    const float* bl1_at = (const float*)d_in[25];
    const float* Wr1_at = (const float*)d_in[26];
    const float* Wl1_ta = (const float*)d_in[27];
    const float* bl1_ta = (const float*)d_in[28];
    const float* Wr1_ta = (const float*)d_in[29];

    const int N = in_sizes[0] / DIN;   // 50000
    const int E = in_sizes[2] / 2;     // 400000

    size_t off = 0;
    char* base = (char*)d_ws;
    auto alloc = [&](size_t bytes) -> void* {
        void* p = base + off;
        off += (bytes + 255) & ~(size_t)255;
        return p;
    };
    int*   cnt    = (int*)  alloc((size_t)4 * N * 4);
    int*   rowptr = (int*)  alloc((size_t)4 * N * 4);
    int*   rank   = (int*)  alloc((size_t)4 * E * 4);
    int*   col    = (int*)  alloc((size_t)4 * E * 4);
    unsigned long long* desc = (unsigned long long*)alloc(257 * 8);
    unsigned short* xb_tx = (unsigned short*)alloc((size_t)N * DIN * 2);
    unsigned short* xb_ad = (unsigned short*)alloc((size_t)N * DIN * 2);
    unsigned short* aggb  = (unsigned short*)alloc((size_t)4 * N * DIN * 2);
    float* z      = (float*)alloc((size_t)4 * N * 2 * 4);
    unsigned short* wb_tt  = (unsigned short*)alloc((size_t)DH * DIN * 2);
    unsigned short* wb_aa  = (unsigned short*)alloc((size_t)DH * DIN * 2);
    unsigned short* wb_at  = (unsigned short*)alloc((size_t)DH * DIN * 2);
    unsigned short* wb_ta  = (unsigned short*)alloc((size_t)DH * DIN * 2);
    unsigned short* wr0c_tx = (unsigned short*)alloc((size_t)DH * DIN * 2);
    unsigned short* wr0c_ad = (unsigned short*)alloc((size_t)DH * DIN * 2);
    float* b0c    = (float*)alloc((size_t)2 * DH * 4);
    float* wzall  = (float*)alloc((size_t)2 * 6 * DH * 4);
    float* b1c    = (float*)alloc((size_t)2 * 2 * 4);
    (void)ws_size;

    float* outp = (float*)d_out;
    const int n4 = 4 * N;

    // 1. setup
    {
        int nconv = N * DIN / 8;
        setup_kernel<<<(nconv + 255) / 256, 256, 0, stream>>>(
            x_tx, x_addr,
            Wl0_tt, Wl0_aa, Wl0_at, Wl0_ta,
            Wr0_tt, Wr0_aa, Wr0_at, Wr0_ta,
            bl0_tt, bl0_aa, bl0_at, bl0_ta,
            Wl1_tt, Wl1_aa, Wl1_at, Wl1_ta,
            Wr1_tt, Wr1_aa, Wr1_at, Wr1_ta,
            bl1_tt, bl1_aa, bl1_at, bl1_ta,
            xb_tx, xb_ad, cnt, desc,
            wb_tt, wb_aa, wb_at, wb_ta, wr0c_tx, wr0c_ad,
            b0c, wzall, b1c, N);
    }
    // 2. counts + ranks
    {
        dim3 g((E + 255) / 256, 4);
        count_kernel<<<g, 256, 0, stream>>>(e_tt, e_aa, e_at, e_ta, cnt, rank, E, N);
    }
    // 3. scan
    {
        int nb = (n4 + 1023) / 1024;
        scan_kernel<<<nb, 1024, 0, stream>>>(cnt, rowptr, desc, n4);
    }
    // 4. fill (no atomics)
    {
        dim3 g((E + 255) / 256, 4);
        fill_kernel<<<g, 256, 0, stream>>>(e_tt, e_aa, e_at, e_ta, rowptr, rank, col, E, N);
    }
    // 5. aggregation
    {
        dim3 g((N + 3) / 4, 4);
        agg_kernel<<<g, 256, 0, stream>>>(xb_tx, xb_ad, rowptr, cnt, col, aggb, N);
    }
    // 6. gemm0 + fused layer-1 transform
    {
        dim3 g((N + 31) / 32, 2);
        gemm0z_kernel<<<g, 256, 0, stream>>>(
            xb_tx, xb_ad, aggb,
            wb_tt, wb_at, wr0c_tx, wb_aa, wb_ta, wr0c_ad,
            b0c, wzall, b1c, z, outp, N);
    }
    // 7. layer-1 aggregation
    {
        dim3 g((N + 255) / 256, 2);
        l1_agg_kernel<<<g, 256, 0, stream>>>(rowptr, cnt, col, z, outp, N);
    }
}

// Round 5
// 394.693 us; speedup vs baseline: 2.3278x; 1.1378x over previous
//
#include <hip/hip_runtime.h>

// HeteroSAGE on MI355X — round 5: gemm0z with LDS-staged A (1x per block),
// M=64 tiles, MFMA-based z epilogue; wave-parallel l1_agg.
//
// Pipeline (7 dispatches):
//   1. setup: zero cnt/desc, x->bf16, fold weights, build bf16 Wz [2][16][256]
//   2. count (y=4): in-degree atomics; stores per-edge rank
//   3. scan: single-kernel decoupled-lookback exclusive prefix
//   4. fill (y=4): col[rowptr[d]+rank[e]] = src (no atomics)
//   5. agg (y=4): per-(node,rel) mean, quarter-wave, 8-edge unroll -> aggb bf16
//   6. gemm0z (y=2): stage A(3 segs x 64 rows) in LDS; 16-MFMA k-iters;
//      h->LDS bf16 (aliased); z via 8 MFMA vs zero-padded Wz; direct stores
//   7. l1_agg (y=2): 8 lanes/node CSR walk, xor-reduce, out += mean(z)

#define DIN 128
#define DH  256
#define LDSA 136    // A-tile row stride (shorts): 128+8 pad -> uniform banks
#define LDSH 264    // h-tile row stride (shorts): 256+8 pad

typedef __attribute__((ext_vector_type(8))) short bf16x8;
typedef __attribute__((ext_vector_type(4))) float f32x4;

__device__ __forceinline__ float bf2f(unsigned int u) {
    return __uint_as_float(u << 16);
}
__device__ __forceinline__ unsigned short f2bf(float f) {
    unsigned int u = __float_as_uint(f);
    u = (u + 0x7fffu + ((u >> 16) & 1u)) >> 16;   // RNE
    return (unsigned short)u;
}
__device__ __forceinline__ void acc_u4(float* a, uint4 u) {
    a[0] += bf2f(u.x & 0xffffu); a[1] += bf2f(u.x >> 16);
    a[2] += bf2f(u.y & 0xffffu); a[3] += bf2f(u.y >> 16);
    a[4] += bf2f(u.z & 0xffffu); a[5] += bf2f(u.z >> 16);
    a[6] += bf2f(u.w & 0xffffu); a[7] += bf2f(u.w >> 16);
}

// ---------------- setup ----------------
__global__ __launch_bounds__(256) void setup_kernel(
    const float* __restrict__ x_tx, const float* __restrict__ x_addr,
    const float* __restrict__ Wl0_tt, const float* __restrict__ Wl0_aa,
    const float* __restrict__ Wl0_at, const float* __restrict__ Wl0_ta,
    const float* __restrict__ Wr0_tt, const float* __restrict__ Wr0_aa,
    const float* __restrict__ Wr0_at, const float* __restrict__ Wr0_ta,
    const float* __restrict__ bl0_tt, const float* __restrict__ bl0_aa,
    const float* __restrict__ bl0_at, const float* __restrict__ bl0_ta,
    const float* __restrict__ Wl1_tt, const float* __restrict__ Wl1_aa,
    const float* __restrict__ Wl1_at, const float* __restrict__ Wl1_ta,
    const float* __restrict__ Wr1_tt, const float* __restrict__ Wr1_aa,
    const float* __restrict__ Wr1_at, const float* __restrict__ Wr1_ta,
    const float* __restrict__ bl1_tt, const float* __restrict__ bl1_aa,
    const float* __restrict__ bl1_at, const float* __restrict__ bl1_ta,
    unsigned short* __restrict__ xb_tx, unsigned short* __restrict__ xb_ad,
    int* __restrict__ cnt, unsigned long long* __restrict__ desc,
    unsigned short* __restrict__ wb_tt, unsigned short* __restrict__ wb_aa,
    unsigned short* __restrict__ wb_at, unsigned short* __restrict__ wb_ta,
    unsigned short* __restrict__ wr0c_tx, unsigned short* __restrict__ wr0c_ad,
    float* __restrict__ b0c, unsigned short* __restrict__ wzb,
    float* __restrict__ b1c, int N)
{
    int i = blockIdx.x * blockDim.x + threadIdx.x;
    int nconv = N * DIN / 8;                 // 800000
    if (i < nconv) {
        {
            const float4* p = (const float4*)(x_tx + (size_t)i * 8);
            float4 a = p[0], b = p[1];
            uint4 o;
            o.x = (unsigned)f2bf(a.x) | ((unsigned)f2bf(a.y) << 16);
            o.y = (unsigned)f2bf(a.z) | ((unsigned)f2bf(a.w) << 16);
            o.z = (unsigned)f2bf(b.x) | ((unsigned)f2bf(b.y) << 16);
            o.w = (unsigned)f2bf(b.z) | ((unsigned)f2bf(b.w) << 16);
            *(uint4*)(xb_tx + (size_t)i * 8) = o;
        }
        {
            const float4* p = (const float4*)(x_addr + (size_t)i * 8);
            float4 a = p[0], b = p[1];
            uint4 o;
            o.x = (unsigned)f2bf(a.x) | ((unsigned)f2bf(a.y) << 16);
            o.y = (unsigned)f2bf(a.z) | ((unsigned)f2bf(a.w) << 16);
            o.z = (unsigned)f2bf(b.x) | ((unsigned)f2bf(b.y) << 16);
            o.w = (unsigned)f2bf(b.z) | ((unsigned)f2bf(b.w) << 16);
            *(uint4*)(xb_ad + (size_t)i * 8) = o;
        }
    }
    if (i < N)                                // 4N ints = N int4
        ((int4*)cnt)[i] = make_int4(0, 0, 0, 0);
    if (i < 257) desc[i] = 0ULL;
    if (i < DH * DIN) {
        wb_tt[i] = f2bf(Wl0_tt[i]);
        wb_aa[i] = f2bf(Wl0_aa[i]);
        wb_at[i] = f2bf(Wl0_at[i]);
        wb_ta[i] = f2bf(Wl0_ta[i]);
        wr0c_tx[i] = f2bf(Wr0_tt[i] + Wr0_at[i]);
        wr0c_ad[i] = f2bf(Wr0_aa[i] + Wr0_ta[i]);
    }
    if (i < DH) {
        b0c[i]      = bl0_tt[i] + bl0_at[i];
        b0c[DH + i] = bl0_aa[i] + bl0_ta[i];
    }
    if (i < 2 * 16 * DH) {                    // wzb: [type][16][256] bf16, rows>=6 zero
        int type = i >> 12;
        int rem = i & 4095;
        int r = rem >> 8;
        int c = rem & 255;
        float v = 0.f;
        if (r < 6) {
            const float* A = type ? Wl1_aa : Wl1_tt;
            const float* B = type ? Wl1_at : Wl1_ta;
            if (r == 0) v = A[c];
            else if (r == 1) v = A[DH + c];
            else if (r == 2) v = B[c];
            else if (r == 3) v = B[DH + c];
            else if (r == 4) v = type ? (Wr1_aa[c] + Wr1_ta[c]) : (Wr1_tt[c] + Wr1_at[c]);
            else             v = type ? (Wr1_aa[DH + c] + Wr1_ta[DH + c])
                                      : (Wr1_tt[DH + c] + Wr1_at[DH + c]);
        }
        wzb[i] = f2bf(v);
    }
    if (i < 2) {
        b1c[i]     = bl1_tt[i] + bl1_at[i];
        b1c[2 + i] = bl1_aa[i] + bl1_ta[i];
    }
}

// ---------------- CSR build ----------------
__global__ __launch_bounds__(256) void count_kernel(
    const int* __restrict__ e0, const int* __restrict__ e1,
    const int* __restrict__ e2, const int* __restrict__ e3,
    int* __restrict__ cnt, int* __restrict__ rank, int E, int N)
{
    int r = blockIdx.y;
    const int* e = (r == 0) ? e0 : (r == 1) ? e1 : (r == 2) ? e2 : e3;
    int i = blockIdx.x * blockDim.x + threadIdx.x;
    if (i < E) {
        int d = e[E + i];
        rank[(size_t)r * E + i] = atomicAdd(&cnt[r * N + d], 1);
    }
}

// single-kernel decoupled-lookback exclusive scan (ticket-ordered)
__global__ __launch_bounds__(1024) void scan_kernel(
    const int* __restrict__ cnt, int* __restrict__ excl,
    unsigned long long* __restrict__ desc, int n)
{
    __shared__ int sdata[1024];
    __shared__ int sseg;
    __shared__ int sprev;
    if (threadIdx.x == 0) sseg = (int)atomicAdd(&desc[256], 1ULL);
    __syncthreads();
    int seg = sseg;
    int i = seg * 1024 + threadIdx.x;
    int v = (i < n) ? cnt[i] : 0;
    sdata[threadIdx.x] = v;
    __syncthreads();
    for (int off = 1; off < 1024; off <<= 1) {
        int t = (threadIdx.x >= off) ? sdata[threadIdx.x - off] : 0;
        __syncthreads();
        sdata[threadIdx.x] += t;
        __syncthreads();
    }
    if (threadIdx.x == 0) {
        int total = sdata[1023];
        int prev = 0;
        if (seg == 0) {
            atomicExch(&desc[0], ((unsigned long long)(unsigned)total << 2) | 2ULL);
        } else {
            atomicExch(&desc[seg], ((unsigned long long)(unsigned)total << 2) | 1ULL);
            int j = seg - 1;
            for (;;) {
                unsigned long long d = atomicAdd(&desc[j], 0ULL);
                unsigned st = (unsigned)(d & 3ULL);
                if (st == 0u) continue;
                prev += (int)(d >> 2);
                if (st == 2u) break;
                --j;
            }
            atomicExch(&desc[seg],
                       ((unsigned long long)(unsigned)(prev + total) << 2) | 2ULL);
        }
        sprev = prev;
    }
    __syncthreads();
    if (i < n) excl[i] = sprev + sdata[threadIdx.x] - v;
}

__global__ __launch_bounds__(256) void fill_kernel(
    const int* __restrict__ e0, const int* __restrict__ e1,
    const int* __restrict__ e2, const int* __restrict__ e3,
    const int* __restrict__ rowptr, const int* __restrict__ rank,
    int* __restrict__ col, int E, int N)
{
    int r = blockIdx.y;
    const int* e = (r == 0) ? e0 : (r == 1) ? e1 : (r == 2) ? e2 : e3;
    int i = blockIdx.x * blockDim.x + threadIdx.x;
    if (i < E) {
        int s = e[i];
        int d = e[E + i];
        col[rowptr[r * N + d] + rank[(size_t)r * E + i]] = s;
    }
}

// ---------------- layer-0 mean aggregation (unchanged from r4) ----------------
__global__ __launch_bounds__(256) void agg_kernel(
    const unsigned short* __restrict__ xb_tx, const unsigned short* __restrict__ xb_ad,
    const int* __restrict__ rowptr, const int* __restrict__ cnt,
    const int* __restrict__ col, unsigned short* __restrict__ aggb, int N)
{
    int r = blockIdx.y;                        // 0=tt 1=aa 2=at 3=ta
    const unsigned short* xs = (r == 0 || r == 3) ? xb_tx : xb_ad;
    int wave = threadIdx.x >> 6;
    int l    = threadIdx.x & 63;
    int node = blockIdx.x * 4 + wave;
    if (node >= N) return;
    int base = rowptr[r * N + node];
    int c    = cnt[r * N + node];
    const int* cl = col + base;
    int q = l >> 4;
    int d = l & 15;
    float acc[8] = {};
    float acc2[8] = {};
    int e0 = 0;
    for (; e0 + 8 <= c; e0 += 8) {
        int sA = cl[e0 + q];
        int sB = cl[e0 + 4 + q];
        uint4 uA = *(const uint4*)(xs + (size_t)sA * DIN + d * 8);
        uint4 uB = *(const uint4*)(xs + (size_t)sB * DIN + d * 8);
        acc_u4(acc, uA);
        acc_u4(acc2, uB);
    }
    for (; e0 < c; e0 += 4) {
        int e = e0 + q;
        if (e < c) {
            int s = cl[e];
            uint4 u = *(const uint4*)(xs + (size_t)s * DIN + d * 8);
            acc_u4(acc, u);
        }
    }
#pragma unroll
    for (int j = 0; j < 8; ++j) {
        acc[j] += acc2[j];
        acc[j] += __shfl_xor(acc[j], 16, 64);
        acc[j] += __shfl_xor(acc[j], 32, 64);
    }
    if (q == 0) {
        float sc = 1.0f / fmaxf((float)c, 1.0f);
        uint4 o;
        o.x = (unsigned)f2bf(acc[0] * sc) | ((unsigned)f2bf(acc[1] * sc) << 16);
        o.y = (unsigned)f2bf(acc[2] * sc) | ((unsigned)f2bf(acc[3] * sc) << 16);
        o.z = (unsigned)f2bf(acc[4] * sc) | ((unsigned)f2bf(acc[5] * sc) << 16);
        o.w = (unsigned)f2bf(acc[6] * sc) | ((unsigned)f2bf(acc[7] * sc) << 16);
        *(uint4*)(aggb + ((size_t)r * N + node) * DIN + d * 8) = o;
    }
}

// ---------------- gemm0 + fused layer-1 transform, LDS-staged A ----------------
// y = dst type. 64 rows/block; 4 waves each own 64 of 256 cols.
// Phase 1: stage A (3 segs x 64 rows x 128) into LDS (once per block).
// Phase 2: K-loop, A from LDS, B (weights) from L2.
// Phase 3: h = relu(acc+bias) -> LDS bf16 (aliases A buffer).
// Phase 4: z = h @ Wz^T via 8 MFMA (Wz zero-padded 16x256 bf16), direct stores.
__global__ __launch_bounds__(256) void gemm0z_kernel(
    const unsigned short* __restrict__ xb_tx, const unsigned short* __restrict__ xb_ad,
    const unsigned short* __restrict__ aggb,
    const unsigned short* __restrict__ wb_tt, const unsigned short* __restrict__ wb_at,
    const unsigned short* __restrict__ wr0c_tx,
    const unsigned short* __restrict__ wb_aa, const unsigned short* __restrict__ wb_ta,
    const unsigned short* __restrict__ wr0c_ad,
    const float* __restrict__ b0c, const unsigned short* __restrict__ wzb,
    const float* __restrict__ b1c,
    float* __restrict__ z, float* __restrict__ outp, int N)
{
    __shared__ unsigned short lds[3 * 64 * LDSA];   // 52224 B; h (64*LDSH) aliases it
    const int type = blockIdx.y;
    const unsigned short* xself = type ? xb_ad : xb_tx;
    const unsigned short* A0 = aggb + (size_t)(type ? 1 : 0) * N * DIN;  // aa / tt
    const unsigned short* A1 = aggb + (size_t)(type ? 3 : 2) * N * DIN;  // ta / at
    const unsigned short* W0 = type ? wb_aa   : wb_tt;
    const unsigned short* W1 = type ? wb_ta   : wb_at;
    const unsigned short* W2 = type ? wr0c_ad : wr0c_tx;
    const float* bias = b0c + type * DH;
    float* zA = type ? (z + (size_t)1 * N * 2) : z;                       // aa / tt
    float* zB = type ? (z + (size_t)2 * N * 2) : (z + (size_t)3 * N * 2); // at / ta
    float* outSelf = outp + (size_t)type * N * 2;

    const int t  = threadIdx.x;
    const int wv = t >> 6;
    const int l  = t & 63;
    const int q  = l >> 4;
    const int lr = l & 15;
    const int m0 = blockIdx.x * 64;
    const int n0 = wv * 64;

    // ---- phase 1: stage A tiles (3072 chunks of 16B; 12 per thread) ----
    {
        const unsigned short* As[3] = {A0, A1, xself};
#pragma unroll
        for (int i = 0; i < 12; ++i) {
            int cid = i * 256 + t;
            int seg = cid >> 10;
            int rem = cid & 1023;
            int row = rem >> 4;
            int ch  = rem & 15;
            int gr = m0 + row; if (gr >= N) gr = N - 1;
            uint4 v = *(const uint4*)(As[seg] + (size_t)gr * DIN + ch * 8);
            *(uint4*)&lds[(seg * 64 + row) * LDSA + ch * 8] = v;
        }
    }
    __syncthreads();

    // ---- phase 2: K-loop ----
    f32x4 accm[4][4] = {};
    {
        const unsigned short* Ws[3] = {W0, W1, W2};
        for (int seg = 0; seg < 3; ++seg) {
            const unsigned short* W = Ws[seg];
            const unsigned short* la = &lds[(seg * 64 + lr) * LDSA + q * 8];
            const unsigned short* pb0 = W + (size_t)(n0 + lr) * DIN + q * 8;
            const unsigned short* pb1 = W + (size_t)(n0 + 16 + lr) * DIN + q * 8;
            const unsigned short* pb2 = W + (size_t)(n0 + 32 + lr) * DIN + q * 8;
            const unsigned short* pb3 = W + (size_t)(n0 + 48 + lr) * DIN + q * 8;
#pragma unroll
            for (int k = 0; k < DIN; k += 32) {
                bf16x8 b0 = *(const bf16x8*)(pb0 + k);
                bf16x8 b1 = *(const bf16x8*)(pb1 + k);
                bf16x8 b2 = *(const bf16x8*)(pb2 + k);
                bf16x8 b3 = *(const bf16x8*)(pb3 + k);
#pragma unroll
                for (int mt = 0; mt < 4; ++mt) {
                    bf16x8 a = *(const bf16x8*)(la + mt * 16 * LDSA + k);
                    accm[mt][0] = __builtin_amdgcn_mfma_f32_16x16x32_bf16(a, b0, accm[mt][0], 0, 0, 0);
                    accm[mt][1] = __builtin_amdgcn_mfma_f32_16x16x32_bf16(a, b1, accm[mt][1], 0, 0, 0);
                    accm[mt][2] = __builtin_amdgcn_mfma_f32_16x16x32_bf16(a, b2, accm[mt][2], 0, 0, 0);
                    accm[mt][3] = __builtin_amdgcn_mfma_f32_16x16x32_bf16(a, b3, accm[mt][3], 0, 0, 0);
                }
            }
        }
    }
    __syncthreads();   // all LDS-A reads done before h overwrites

    // ---- phase 3: h = relu(acc + bias) -> LDS bf16 ----
    {
        float bias_nt[4];
#pragma unroll
        for (int nt = 0; nt < 4; ++nt) bias_nt[nt] = bias[n0 + nt * 16 + lr];
#pragma unroll
        for (int mt = 0; mt < 4; ++mt) {
#pragma unroll
            for (int nt = 0; nt < 4; ++nt) {
                int colc = n0 + nt * 16 + lr;
#pragma unroll
                for (int rr = 0; rr < 4; ++rr) {
                    int row = mt * 16 + q * 4 + rr;
                    lds[row * LDSH + colc] =
                        f2bf(fmaxf(accm[mt][nt][rr] + bias_nt[nt], 0.f));
                }
            }
        }
    }
    __syncthreads();

    // ---- phase 4: z = h @ Wz^T (one 16-row m-tile per wave) ----
    {
        const unsigned short* wz = wzb + (size_t)type * 16 * DH;
        f32x4 az = {};
        const unsigned short* la = &lds[(wv * 16 + lr) * LDSH + q * 8];
        const unsigned short* pb = wz + lr * DH + q * 8;
#pragma unroll
        for (int k = 0; k < DH; k += 32) {
            bf16x8 a = *(const bf16x8*)(la + k);
            bf16x8 b = *(const bf16x8*)(pb + k);
            az = __builtin_amdgcn_mfma_f32_16x16x32_bf16(a, b, az, 0, 0, 0);
        }
        // D layout: row = q*4+reg (within m-tile), col (zi) = lr
        if (lr < 6) {
#pragma unroll
            for (int reg = 0; reg < 4; ++reg) {
                int node = m0 + wv * 16 + q * 4 + reg;
                if (node < N) {
                    float v = az[reg];
                    if (lr < 2)      zA[node * 2 + lr] = v;
                    else if (lr < 4) zB[node * 2 + lr - 2] = v;
                    else             outSelf[node * 2 + lr - 4] = v + b1c[type * 2 + lr - 4];
                }
            }
        }
    }
}

// ---------------- layer-1 aggregate (y=2): 8 lanes per node ----------------
__global__ __launch_bounds__(256) void l1_agg_kernel(
    const int* __restrict__ rowptr, const int* __restrict__ cnt, const int* __restrict__ col,
    const float* __restrict__ z, float* __restrict__ out, int N)
{
    const int type = blockIdx.y;
    const int rA = type ? 1 : 0;
    const int rB = type ? 3 : 2;
    const float* zAp = type ? (z + (size_t)1 * N * 2) : z;
    const float* zBp = type ? (z + (size_t)3 * N * 2) : (z + (size_t)2 * N * 2);
    float* outp = out + (size_t)type * N * 2;

    const int t = threadIdx.x;
    const int wave = t >> 6;
    const int l = t & 63;
    const int sub = l >> 3;       // node within wave's 8
    const int es  = l & 7;        // edge slot
    int node = blockIdx.x * 32 + wave * 8 + sub;
    bool valid = node < N;

    float ax = 0.f, ay = 0.f;
#pragma unroll
    for (int ri = 0; ri < 2; ++ri) {
        int rel = ri ? rB : rA;
        const float* zp = ri ? zBp : zAp;
        int b = 0, c = 0;
        if (valid) { b = rowptr[rel * N + node]; c = cnt[rel * N + node]; }
        const int* cl = col + b;
        float sx = 0.f, sy = 0.f;
        for (int e = es; e < c; e += 8) {
            int s = cl[e];
            float2 v = *(const float2*)(zp + (size_t)s * 2);
            sx += v.x; sy += v.y;
        }
        sx += __shfl_xor(sx, 1, 64); sy += __shfl_xor(sy, 1, 64);
        sx += __shfl_xor(sx, 2, 64); sy += __shfl_xor(sy, 2, 64);
        sx += __shfl_xor(sx, 4, 64); sy += __shfl_xor(sy, 4, 64);
        float sc = 1.0f / fmaxf((float)c, 1.0f);
        ax += sx * sc; ay += sy * sc;
    }
    if (valid && es == 0) {
        float2 o = *(float2*)(outp + (size_t)node * 2);   // self term from gemm0z
        o.x += ax; o.y += ay;
        *(float2*)(outp + (size_t)node * 2) = o;
    }
}

// ---------------- launch ----------------
extern "C" void kernel_launch(void* const* d_in, const int* in_sizes, int n_in,
                              void* d_out, int out_size, void* d_ws, size_t ws_size,
                              hipStream_t stream)
{
    const float* x_tx   = (const float*)d_in[0];
    const float* x_addr = (const float*)d_in[1];
    const int* e_tt = (const int*)d_in[2];
    const int* e_aa = (const int*)d_in[3];
    const int* e_at = (const int*)d_in[4];
    const int* e_ta = (const int*)d_in[5];
    const float* Wl0_tt = (const float*)d_in[6];
    const float* bl0_tt = (const float*)d_in[7];
    const float* Wr0_tt = (const float*)d_in[8];
    const float* Wl0_aa = (const float*)d_in[9];
    const float* bl0_aa = (const float*)d_in[10];
    const float* Wr0_aa = (const float*)d_in[11];
    const float* Wl0_at = (const float*)d_in[12];
    const float* bl0_at = (const float*)d_in[13];
    const float* Wr0_at = (const float*)d_in[14];
    const float* Wl0_ta = (const float*)d_in[15];
    const float* bl0_ta = (const float*)d_in[16];
    const float* Wr0_ta = (const float*)d_in[17];
    const float* Wl1_tt = (const float*)d_in[18];
    const float* bl1_tt = (const float*)d_in[19];
    const float* Wr1_tt = (const float*)d_in[20];
    const float* Wl1_aa = (const float*)d_in[21];
    const float* bl1_aa = (const float*)d_in[22];
    const float* Wr1_aa = (const float*)d_in[23];
    const float* Wl1_at = (const float*)d_in[24];
    const float* bl1_at = (const float*)d_in[25];
    const float* Wr1_at = (const float*)d_in[26];
    const float* Wl1_ta = (const float*)d_in[27];
    const float* bl1_ta = (const float*)d_in[28];
    const float* Wr1_ta = (const float*)d_in[29];

    const int N = in_sizes[0] / DIN;   // 50000
    const int E = in_sizes[2] / 2;     // 400000

    size_t off = 0;
    char* base = (char*)d_ws;
    auto alloc = [&](size_t bytes) -> void* {
        void* p = base + off;
        off += (bytes + 255) & ~(size_t)255;
        return p;
    };
    int*   cnt    = (int*)  alloc((size_t)4 * N * 4);
    int*   rowptr = (int*)  alloc((size_t)4 * N * 4);
    int*   rank   = (int*)  alloc((size_t)4 * E * 4);
    int*   col    = (int*)  alloc((size_t)4 * E * 4);
    unsigned long long* desc = (unsigned long long*)alloc(257 * 8);
    unsigned short* xb_tx = (unsigned short*)alloc((size_t)N * DIN * 2);
    unsigned short* xb_ad = (unsigned short*)alloc((size_t)N * DIN * 2);
    unsigned short* aggb  = (unsigned short*)alloc((size_t)4 * N * DIN * 2);
    float* z      = (float*)alloc((size_t)4 * N * 2 * 4);
    unsigned short* wb_tt  = (unsigned short*)alloc((size_t)DH * DIN * 2);
    unsigned short* wb_aa  = (unsigned short*)alloc((size_t)DH * DIN * 2);
    unsigned short* wb_at  = (unsigned short*)alloc((size_t)DH * DIN * 2);
    unsigned short* wb_ta  = (unsigned short*)alloc((size_t)DH * DIN * 2);
    unsigned short* wr0c_tx = (unsigned short*)alloc((size_t)DH * DIN * 2);
    unsigned short* wr0c_ad = (unsigned short*)alloc((size_t)DH * DIN * 2);
    float* b0c    = (float*)alloc((size_t)2 * DH * 4);
    unsigned short* wzb = (unsigned short*)alloc((size_t)2 * 16 * DH * 2);
    float* b1c    = (float*)alloc((size_t)2 * 2 * 4);
    (void)ws_size;

    float* outp = (float*)d_out;
    const int n4 = 4 * N;

    // 1. setup
    {
        int nconv = N * DIN / 8;
        setup_kernel<<<(nconv + 255) / 256, 256, 0, stream>>>(
            x_tx, x_addr,
            Wl0_tt, Wl0_aa, Wl0_at, Wl0_ta,
            Wr0_tt, Wr0_aa, Wr0_at, Wr0_ta,
            bl0_tt, bl0_aa, bl0_at, bl0_ta,
            Wl1_tt, Wl1_aa, Wl1_at, Wl1_ta,
            Wr1_tt, Wr1_aa, Wr1_at, Wr1_ta,
            bl1_tt, bl1_aa, bl1_at, bl1_ta,
            xb_tx, xb_ad, cnt, desc,
            wb_tt, wb_aa, wb_at, wb_ta, wr0c_tx, wr0c_ad,
            b0c, wzb, b1c, N);
    }
    // 2. counts + ranks
    {
        dim3 g((E + 255) / 256, 4);
        count_kernel<<<g, 256, 0, stream>>>(e_tt, e_aa, e_at, e_ta, cnt, rank, E, N);
    }
    // 3. scan
    {
        int nb = (n4 + 1023) / 1024;
        scan_kernel<<<nb, 1024, 0, stream>>>(cnt, rowptr, desc, n4);
    }
    // 4. fill (no atomics)
    {
        dim3 g((E + 255) / 256, 4);
        fill_kernel<<<g, 256, 0, stream>>>(e_tt, e_aa, e_at, e_ta, rowptr, rank, col, E, N);
    }
    // 5. aggregation
    {
        dim3 g((N + 3) / 4, 4);
        agg_kernel<<<g, 256, 0, stream>>>(xb_tx, xb_ad, rowptr, cnt, col, aggb, N);
    }
    // 6. gemm0 + fused layer-1 transform
    {
        dim3 g((N + 63) / 64, 2);
        gemm0z_kernel<<<g, 256, 0, stream>>>(
            xb_tx, xb_ad, aggb,
            wb_tt, wb_at, wr0c_tx, wb_aa, wb_ta, wr0c_ad,
            b0c, wzb, b1c, z, outp, N);
    }
    // 7. layer-1 aggregation
    {
        dim3 g((N + 31) / 32, 2);
        l1_agg_kernel<<<g, 256, 0, stream>>>(rowptr, cnt, col, z, outp, N);
    }
}